// Round 3
// baseline (2387.656 us; speedup 1.0000x reference)
//
#include <hip/hip_runtime.h>

// Problem constants (match reference)
#define BG   8          // graphs
#define NN   10000      // nodes per graph
#define EE   320000     // edges per graph
#define CC   128        // channels (in == out)
#define BN   (BG*NN)    // 80000
#define BE   (BG*EE)    // 2560000

#define NBKT   100      // buckets per graph (100 rows each)
#define BROWS  100      // rows per bucket
#define CHUNK  4096     // edges per binning block
#define BPG    ((EE + CHUNK - 1) / CHUNK)   // 79 blocks per graph

// bucket(row) = floor(row/100) via multiply-shift (exact for row < 10486)
__device__ __forceinline__ int bucket_of(int r) { return (r * 5243) >> 19; }

// ---------------------------------------------------------------------------
// Workspace layout:
//   [0, BE)                 binned edges (int2: meta=(row_local<<14|col), val bits)  20.48 MB
//   then deg     (BN f32)
//   then counts  (800 int)   <- memset 0 each call
//   then offsets (800 int)
//   then gcursor (800 int)
// total ~20.8 MB
// aggx (sum v*x[col]) accumulates into d_out, overwritten in place by k_gemm.
// ---------------------------------------------------------------------------

__global__ __launch_bounds__(256) void k_bhist(const int* __restrict__ edge_row,
                                               int* __restrict__ counts) {
    int g = blockIdx.x / BPG;
    int cstart = (blockIdx.x % BPG) * CHUNK;
    int t = threadIdx.x;
    __shared__ int lh[NBKT];
    if (t < NBKT) lh[t] = 0;
    __syncthreads();
#pragma unroll
    for (int j = 0; j < CHUNK / 256; j++) {
        int e = cstart + j * 256 + t;
        if (e < EE) {
            int r = edge_row[(size_t)g * EE + e];
            atomicAdd(&lh[bucket_of(r)], 1);
        }
    }
    __syncthreads();
    if (t < NBKT && lh[t]) atomicAdd(&counts[g * NBKT + t], lh[t]);
}

// exclusive scan of counts per graph (8 graphs x 100 bins); one block.
__global__ __launch_bounds__(1024) void k_scan(const int* __restrict__ counts,
                                               int* __restrict__ offsets,
                                               int* __restrict__ gcursor) {
    __shared__ int s[1024];
    int t = threadIdx.x;
    int g = t >> 7, i = t & 127;
    int own = (i < NBKT) ? counts[g * NBKT + i] : 0;
    s[t] = own;
    __syncthreads();
#pragma unroll
    for (int d = 1; d < 128; d <<= 1) {
        int add = (i >= d) ? s[t - d] : 0;
        __syncthreads();
        s[t] += add;
        __syncthreads();
    }
    if (i < NBKT) {
        int ex = s[t] - own;
        offsets[g * NBKT + i] = ex;
        gcursor[g * NBKT + i] = ex;
    }
}

__global__ __launch_bounds__(256) void k_bin(const int* __restrict__ edge_row,
                                             const int* __restrict__ edge_col,
                                             const float* __restrict__ edge_val,
                                             int* __restrict__ gcursor,
                                             int2* __restrict__ binned) {
    int g = blockIdx.x / BPG;
    int cstart = (blockIdx.x % BPG) * CHUNK;
    int t = threadIdx.x;
    __shared__ int lh[NBKT];
    __shared__ int lbase[NBKT];
    if (t < NBKT) lh[t] = 0;
    __syncthreads();
    int rows[CHUNK / 256];
#pragma unroll
    for (int j = 0; j < CHUNK / 256; j++) {
        int e = cstart + j * 256 + t;
        if (e < EE) {
            int r = edge_row[(size_t)g * EE + e];
            rows[j] = r;
            atomicAdd(&lh[bucket_of(r)], 1);
        } else rows[j] = -1;
    }
    __syncthreads();
    if (t < NBKT) lbase[t] = lh[t] ? atomicAdd(&gcursor[g * NBKT + t], lh[t]) : 0;
    __syncthreads();
    if (t < NBKT) lh[t] = 0;
    __syncthreads();
#pragma unroll
    for (int j = 0; j < CHUNK / 256; j++) {
        if (rows[j] >= 0) {
            int e = cstart + j * 256 + t;
            int r = rows[j];
            int bin = bucket_of(r);
            int pos = lbase[bin] + atomicAdd(&lh[bin], 1);
            int col = edge_col[(size_t)g * EE + e];
            float v = edge_val[(size_t)g * EE + e];
            binned[(size_t)g * EE + pos] =
                make_int2(((r - bin * BROWS) << 14) | col, __float_as_int(v));
        }
    }
}

// One block per (graph, bucket): LDS-accumulate 100 rows x 128 ch.
// blockIdx%8 = graph -> XCD L2 affinity for that graph's x (5.1 MB).
__global__ __launch_bounds__(256) void k_gather(const float* __restrict__ x,
                                                const int* __restrict__ offsets,
                                                const int* __restrict__ counts,
                                                const int2* __restrict__ binned,
                                                float* __restrict__ aggx,
                                                float* __restrict__ deg) {
    int g = blockIdx.x & 7;
    int bkt = blockIdx.x >> 3;
    int t = threadIdx.x;
    int wid = t >> 6, lane = t & 63;

    __shared__ __align__(16) float acc[BROWS * CC];   // 51.2 KB
    __shared__ float dl[BROWS];

    float4 z = make_float4(0.f, 0.f, 0.f, 0.f);
#pragma unroll
    for (int it = 0; it < 13; it++) {
        int f4 = t + it * 256;
        if (f4 < BROWS * CC / 4) *(float4*)(&acc[f4 * 4]) = z;
    }
    if (t < BROWS) dl[t] = 0.f;
    __syncthreads();

    int start = offsets[g * NBKT + bkt];
    int len = counts[g * NBKT + bkt];
    const int2* ep = binned + (size_t)g * EE + start;
    const float* xb = x + (size_t)g * NN * CC;

    for (int base = wid * 64; base < len; base += 256) {
        bool active = (base + lane) < len;
        int2 ed = active ? ep[base + lane] : make_int2(0, 0);
        if (active) atomicAdd(&dl[ed.x >> 14], __int_as_float(ed.y));
        int m = len - base; if (m > 64) m = 64;
        int e = 0;
        for (; e + 4 <= m; e += 4) {
            int m0 = __shfl(ed.x, e + 0); float v0 = __int_as_float(__shfl(ed.y, e + 0));
            int m1 = __shfl(ed.x, e + 1); float v1 = __int_as_float(__shfl(ed.y, e + 1));
            int m2 = __shfl(ed.x, e + 2); float v2 = __int_as_float(__shfl(ed.y, e + 2));
            int m3 = __shfl(ed.x, e + 3); float v3 = __int_as_float(__shfl(ed.y, e + 3));
            float2 x0 = *(const float2*)(xb + (size_t)(m0 & 0x3FFF) * CC + 2 * lane);
            float2 x1 = *(const float2*)(xb + (size_t)(m1 & 0x3FFF) * CC + 2 * lane);
            float2 x2 = *(const float2*)(xb + (size_t)(m2 & 0x3FFF) * CC + 2 * lane);
            float2 x3 = *(const float2*)(xb + (size_t)(m3 & 0x3FFF) * CC + 2 * lane);
            int r0 = m0 >> 14, r1 = m1 >> 14, r2 = m2 >> 14, r3 = m3 >> 14;
            atomicAdd(&acc[r0 * CC + 2 * lane],     v0 * x0.x);
            atomicAdd(&acc[r0 * CC + 2 * lane + 1], v0 * x0.y);
            atomicAdd(&acc[r1 * CC + 2 * lane],     v1 * x1.x);
            atomicAdd(&acc[r1 * CC + 2 * lane + 1], v1 * x1.y);
            atomicAdd(&acc[r2 * CC + 2 * lane],     v2 * x2.x);
            atomicAdd(&acc[r2 * CC + 2 * lane + 1], v2 * x2.y);
            atomicAdd(&acc[r3 * CC + 2 * lane],     v3 * x3.x);
            atomicAdd(&acc[r3 * CC + 2 * lane + 1], v3 * x3.y);
        }
        for (; e < m; e++) {
            int mm = __shfl(ed.x, e); float vv = __int_as_float(__shfl(ed.y, e));
            float2 xv = *(const float2*)(xb + (size_t)(mm & 0x3FFF) * CC + 2 * lane);
            int rr = mm >> 14;
            atomicAdd(&acc[rr * CC + 2 * lane],     vv * xv.x);
            atomicAdd(&acc[rr * CC + 2 * lane + 1], vv * xv.y);
        }
    }
    __syncthreads();

    size_t rowbase = (size_t)g * NN + (size_t)bkt * BROWS;
#pragma unroll
    for (int it = 0; it < 13; it++) {
        int f4 = t + it * 256;
        if (f4 < BROWS * CC / 4) {
            int rl = f4 >> 5, c4 = f4 & 31;
            *(float4*)(aggx + (rowbase + rl) * CC + c4 * 4) = *(float4*)(&acc[f4 * 4]);
        }
    }
    if (t < BROWS) deg[rowbase + t] = dl[t];
}

// out[row] = mask * (aggx[row] @ W + deg*bias) / max(deg,1)
// 64 rows x 128 cols per block; thread tile 4 rows x 8 cols.
__global__ __launch_bounds__(256) void k_gemm(float* __restrict__ io,
                                              const float* __restrict__ W,
                                              const float* __restrict__ bias,
                                              const float* __restrict__ deg,
                                              const int* __restrict__ num_nodes) {
    __shared__ float at[64][132];
    int t = threadIdx.x;
    int row0 = blockIdx.x * 64;

    const float4* src = (const float4*)(io + (size_t)row0 * CC);
#pragma unroll
    for (int i = 0; i < 8; i++) {
        int f4 = t + i * 256;
        float4 v = src[f4];
        int row = f4 >> 5;
        int col4 = f4 & 31;
        *(float4*)(&at[row][col4 * 4]) = v;
    }
    __syncthreads();

    int cg = t & 15;
    int rg = t >> 4;
    float acc[4][8] = {};
#pragma unroll 4
    for (int k = 0; k < 128; k++) {
        float4 w0 = *(const float4*)(W + k * 128 + cg * 8);
        float4 w1 = *(const float4*)(W + k * 128 + cg * 8 + 4);
        float a0 = at[rg * 4 + 0][k];
        float a1 = at[rg * 4 + 1][k];
        float a2 = at[rg * 4 + 2][k];
        float a3 = at[rg * 4 + 3][k];
        acc[0][0] += a0 * w0.x; acc[0][1] += a0 * w0.y; acc[0][2] += a0 * w0.z; acc[0][3] += a0 * w0.w;
        acc[0][4] += a0 * w1.x; acc[0][5] += a0 * w1.y; acc[0][6] += a0 * w1.z; acc[0][7] += a0 * w1.w;
        acc[1][0] += a1 * w0.x; acc[1][1] += a1 * w0.y; acc[1][2] += a1 * w0.z; acc[1][3] += a1 * w0.w;
        acc[1][4] += a1 * w1.x; acc[1][5] += a1 * w1.y; acc[1][6] += a1 * w1.z; acc[1][7] += a1 * w1.w;
        acc[2][0] += a2 * w0.x; acc[2][1] += a2 * w0.y; acc[2][2] += a2 * w0.z; acc[2][3] += a2 * w0.w;
        acc[2][4] += a2 * w1.x; acc[2][5] += a2 * w1.y; acc[2][6] += a2 * w1.z; acc[2][7] += a2 * w1.w;
        acc[3][0] += a3 * w0.x; acc[3][1] += a3 * w0.y; acc[3][2] += a3 * w0.z; acc[3][3] += a3 * w0.w;
        acc[3][4] += a3 * w1.x; acc[3][5] += a3 * w1.y; acc[3][6] += a3 * w1.z; acc[3][7] += a3 * w1.w;
    }

    float4 b0 = *(const float4*)(bias + cg * 8);
    float4 b1 = *(const float4*)(bias + cg * 8 + 4);
    float bb[8] = { b0.x, b0.y, b0.z, b0.w, b1.x, b1.y, b1.z, b1.w };

#pragma unroll
    for (int i = 0; i < 4; i++) {
        int grow = row0 + rg * 4 + i;
        int b = grow / NN;
        int r = grow - b * NN;
        float d = deg[grow];
        float sc = 1.0f / fmaxf(d, 1.0f);
        bool alive = r < num_nodes[b];
        float o[8];
#pragma unroll
        for (int j = 0; j < 8; j++)
            o[j] = alive ? (acc[i][j] + d * bb[j]) * sc : 0.0f;
        float* dst = io + (size_t)grow * CC + cg * 8;
        *(float4*)(dst)     = make_float4(o[0], o[1], o[2], o[3]);
        *(float4*)(dst + 4) = make_float4(o[4], o[5], o[6], o[7]);
    }
}

extern "C" void kernel_launch(void* const* d_in, const int* in_sizes, int n_in,
                              void* d_out, int out_size, void* d_ws, size_t ws_size,
                              hipStream_t stream) {
    const float* x        = (const float*)d_in[0];
    const float* weight   = (const float*)d_in[1];
    const float* bias     = (const float*)d_in[2];
    const int*   edge_row = (const int*)d_in[3];
    const int*   edge_col = (const int*)d_in[4];
    const float* edge_val = (const float*)d_in[5];
    const int*   num_nodes= (const int*)d_in[6];
    float* out = (float*)d_out;

    int2*  binned  = (int2*)d_ws;                       // BE int2
    float* deg     = (float*)d_ws + 2 * (size_t)BE;     // BN f32
    int*   counts  = (int*)d_ws + 2 * (size_t)BE + BN;  // 800
    int*   offsets = counts + BG * NBKT;
    int*   gcursor = offsets + BG * NBKT;

    hipMemsetAsync(counts, 0, BG * NBKT * sizeof(int), stream);
    k_bhist<<<BG * BPG, 256, 0, stream>>>(edge_row, counts);
    k_scan<<<1, 1024, 0, stream>>>(counts, offsets, gcursor);
    k_bin<<<BG * BPG, 256, 0, stream>>>(edge_row, edge_col, edge_val, gcursor, binned);
    k_gather<<<BG * NBKT, 256, 0, stream>>>(x, offsets, counts, binned, out, deg);
    k_gemm<<<BN / 64, 256, 0, stream>>>(out, weight, bias, deg, num_nodes);
}

// Round 4
// 386.652 us; speedup vs baseline: 6.1752x; 6.1752x over previous
//
#include <hip/hip_runtime.h>

// Problem constants (match reference)
#define BG   8          // graphs
#define NN   10000      // nodes per graph
#define EE   320000     // edges per graph
#define CC   128        // channels (in == out)
#define BN   (BG*NN)    // 80000
#define BE   (BG*EE)    // 2560000

#define NBKT   100      // buckets per graph (100 rows each)
#define BROWS  100      // rows per bucket
#define CHUNK  4096     // edges per binning block
#define BPG    ((EE + CHUNK - 1) / CHUNK)   // 79 blocks per graph

// bucket(row) = floor(row/100) via multiply-shift (exact for row < 10486)
__device__ __forceinline__ int bucket_of(int r) { return (r * 5243) >> 19; }

// ---------------------------------------------------------------------------
// Buffers:
//   d_out (41 MB) doubles as the phase-A "binned" buffer (BE int2 = 20.5 MB),
//   consumed by k_sort before k_gather overwrites d_out with aggx.
// Workspace layout:
//   [0, BE) int2            sorted edges {col, val_bits}, row-sorted per graph
//   then deg      (BN f32)
//   then row_off  (BN int)   within-graph edge index of each row's segment
//   then row_cnt  (BN int)
//   then counts   (800 int)  bucket counts   <- memset 0 each call
//   then offsets  (800 int)  bucket excl scan (within graph)
//   then gcursor  (800 int)
// total ~21.5 MB
// ---------------------------------------------------------------------------

__global__ __launch_bounds__(256) void k_bhist(const int* __restrict__ edge_row,
                                               int* __restrict__ counts) {
    int g = blockIdx.x / BPG;
    int cstart = (blockIdx.x % BPG) * CHUNK;
    int t = threadIdx.x;
    __shared__ int lh[NBKT];
    if (t < NBKT) lh[t] = 0;
    __syncthreads();
#pragma unroll
    for (int j = 0; j < CHUNK / 256; j++) {
        int e = cstart + j * 256 + t;
        if (e < EE) {
            int r = edge_row[(size_t)g * EE + e];
            atomicAdd(&lh[bucket_of(r)], 1);
        }
    }
    __syncthreads();
    if (t < NBKT && lh[t]) atomicAdd(&counts[g * NBKT + t], lh[t]);
}

// exclusive scan of bucket counts per graph (8 x 100); one block.
__global__ __launch_bounds__(1024) void k_scan(const int* __restrict__ counts,
                                               int* __restrict__ offsets,
                                               int* __restrict__ gcursor) {
    __shared__ int s[1024];
    int t = threadIdx.x;
    int g = t >> 7, i = t & 127;
    int own = (i < NBKT) ? counts[g * NBKT + i] : 0;
    s[t] = own;
    __syncthreads();
#pragma unroll
    for (int d = 1; d < 128; d <<= 1) {
        int add = (i >= d) ? s[t - d] : 0;
        __syncthreads();
        s[t] += add;
        __syncthreads();
    }
    if (i < NBKT) {
        int ex = s[t] - own;
        offsets[g * NBKT + i] = ex;
        gcursor[g * NBKT + i] = ex;
    }
}

__global__ __launch_bounds__(256) void k_bin(const int* __restrict__ edge_row,
                                             const int* __restrict__ edge_col,
                                             const float* __restrict__ edge_val,
                                             int* __restrict__ gcursor,
                                             int2* __restrict__ binned) {
    int g = blockIdx.x / BPG;
    int cstart = (blockIdx.x % BPG) * CHUNK;
    int t = threadIdx.x;
    __shared__ int lh[NBKT];
    __shared__ int lbase[NBKT];
    if (t < NBKT) lh[t] = 0;
    __syncthreads();
    int rows[CHUNK / 256];
#pragma unroll
    for (int j = 0; j < CHUNK / 256; j++) {
        int e = cstart + j * 256 + t;
        if (e < EE) {
            int r = edge_row[(size_t)g * EE + e];
            rows[j] = r;
            atomicAdd(&lh[bucket_of(r)], 1);
        } else rows[j] = -1;
    }
    __syncthreads();
    if (t < NBKT) lbase[t] = lh[t] ? atomicAdd(&gcursor[g * NBKT + t], lh[t]) : 0;
    __syncthreads();
    if (t < NBKT) lh[t] = 0;
    __syncthreads();
#pragma unroll
    for (int j = 0; j < CHUNK / 256; j++) {
        if (rows[j] >= 0) {
            int e = cstart + j * 256 + t;
            int r = rows[j];
            int bin = bucket_of(r);
            int pos = lbase[bin] + atomicAdd(&lh[bin], 1);
            int col = edge_col[(size_t)g * EE + e];
            float v = edge_val[(size_t)g * EE + e];
            binned[(size_t)g * EE + pos] =
                make_int2(((r - bin * BROWS) << 14) | col, __float_as_int(v));
        }
    }
}

// One block per (graph, bucket): counting-sort the bucket's edges by row.
// Reads binned (L2-hot, two passes), writes {col,val} into sorted, and emits
// per-row offsets/counts for the gather.
__global__ __launch_bounds__(256) void k_sort(const int2* __restrict__ binned,
                                              const int* __restrict__ boff,
                                              const int* __restrict__ bcnt,
                                              int2* __restrict__ sorted,
                                              int* __restrict__ row_off,
                                              int* __restrict__ row_cnt) {
    int g = blockIdx.x / NBKT;
    int bkt = blockIdx.x % NBKT;
    int t = threadIdx.x;
    __shared__ int cnts[BROWS], excl[BROWS], curs[BROWS];
    if (t < BROWS) cnts[t] = 0;
    __syncthreads();
    int start = boff[g * NBKT + bkt];
    int cnt = bcnt[g * NBKT + bkt];
    const int2* src = binned + (size_t)g * EE + start;
    for (int i = t; i < cnt; i += 256)
        atomicAdd(&cnts[src[i].x >> 14], 1);
    __syncthreads();
    if (t == 0) {
        int a = 0;
        for (int i = 0; i < BROWS; i++) { excl[i] = a; a += cnts[i]; }
    }
    __syncthreads();
    if (t < BROWS) {
        curs[t] = excl[t];
        int row = g * NN + bkt * BROWS + t;
        row_off[row] = start + excl[t];
        row_cnt[row] = cnts[t];
    }
    __syncthreads();
    int2* dst = sorted + (size_t)g * EE + start;
    for (int i = t; i < cnt; i += 256) {
        int2 ed = src[i];
        int pos = atomicAdd(&curs[ed.x >> 14], 1);
        dst[pos] = make_int2(ed.x & 0x3FFF, ed.y);
    }
}

// One wave per row, register accumulation, 8 edges in flight, software-
// pipelined meta prefetch. No LDS, no atomics. bid&7 = graph -> XCD affinity.
__global__ __launch_bounds__(256) void k_gather(const float* __restrict__ x,
                                                const int* __restrict__ row_off,
                                                const int* __restrict__ row_cnt,
                                                const int2* __restrict__ sorted,
                                                float* __restrict__ aggx,
                                                float* __restrict__ deg) {
    int bid = blockIdx.x;
    int g = bid & 7;
    int chunk = bid >> 3;                     // 0..2499
    int wid = threadIdx.x >> 6, lane = threadIdx.x & 63;
    int r = chunk * 4 + wid;
    int bn = g * NN + r;
    int start = row_off[bn];
    int cnt = row_cnt[bn];
    const int2* ep = sorted + (size_t)g * EE + start;
    const float* xb = x + (size_t)g * NN * CC + 2 * lane;

    float2 aa[4];
#pragma unroll
    for (int j = 0; j < 4; j++) aa[j] = make_float2(0.f, 0.f);
    float dsum = 0.f;

    int2 cur[8];
    if (cnt > 0) {
#pragma unroll
        for (int j = 0; j < 8; j++) cur[j] = ep[(j < cnt) ? j : 0];
    }
    for (int e = 0; e < cnt; e += 8) {
        int n = cnt - e;
        float2 xv[8];
#pragma unroll
        for (int j = 0; j < 8; j++)
            xv[j] = *(const float2*)(xb + (size_t)cur[j].x * CC);
        bool more = (e + 8) < cnt;
        int2 nxt[8];
        if (more) {
#pragma unroll
            for (int j = 0; j < 8; j++) {
                int idx = e + 8 + j;
                nxt[j] = ep[(idx < cnt) ? idx : (cnt - 1)];
            }
        }
#pragma unroll
        for (int j = 0; j < 8; j++) {
            float v = (j < n) ? __int_as_float(cur[j].y) : 0.f;
            aa[j & 3].x += v * xv[j].x;
            aa[j & 3].y += v * xv[j].y;
            dsum += v;
        }
        if (more) {
#pragma unroll
            for (int j = 0; j < 8; j++) cur[j] = nxt[j];
        }
    }
    float2 res = make_float2(aa[0].x + aa[1].x + aa[2].x + aa[3].x,
                             aa[0].y + aa[1].y + aa[2].y + aa[3].y);
    *(float2*)(aggx + (size_t)bn * CC + 2 * lane) = res;
    if (lane == 0) deg[bn] = dsum;
}

// out[row] = mask * (aggx[row] @ W + deg*bias) / max(deg,1)
__global__ __launch_bounds__(256) void k_gemm(float* __restrict__ io,
                                              const float* __restrict__ W,
                                              const float* __restrict__ bias,
                                              const float* __restrict__ deg,
                                              const int* __restrict__ num_nodes) {
    __shared__ float at[64][132];
    int t = threadIdx.x;
    int row0 = blockIdx.x * 64;

    const float4* src = (const float4*)(io + (size_t)row0 * CC);
#pragma unroll
    for (int i = 0; i < 8; i++) {
        int f4 = t + i * 256;
        float4 v = src[f4];
        int row = f4 >> 5;
        int col4 = f4 & 31;
        *(float4*)(&at[row][col4 * 4]) = v;
    }
    __syncthreads();

    int cg = t & 15;
    int rg = t >> 4;
    float acc[4][8] = {};
#pragma unroll 4
    for (int k = 0; k < 128; k++) {
        float4 w0 = *(const float4*)(W + k * 128 + cg * 8);
        float4 w1 = *(const float4*)(W + k * 128 + cg * 8 + 4);
        float a0 = at[rg * 4 + 0][k];
        float a1 = at[rg * 4 + 1][k];
        float a2 = at[rg * 4 + 2][k];
        float a3 = at[rg * 4 + 3][k];
        acc[0][0] += a0 * w0.x; acc[0][1] += a0 * w0.y; acc[0][2] += a0 * w0.z; acc[0][3] += a0 * w0.w;
        acc[0][4] += a0 * w1.x; acc[0][5] += a0 * w1.y; acc[0][6] += a0 * w1.z; acc[0][7] += a0 * w1.w;
        acc[1][0] += a1 * w0.x; acc[1][1] += a1 * w0.y; acc[1][2] += a1 * w0.z; acc[1][3] += a1 * w0.w;
        acc[1][4] += a1 * w1.x; acc[1][5] += a1 * w1.y; acc[1][6] += a1 * w1.z; acc[1][7] += a1 * w1.w;
        acc[2][0] += a2 * w0.x; acc[2][1] += a2 * w0.y; acc[2][2] += a2 * w0.z; acc[2][3] += a2 * w0.w;
        acc[2][4] += a2 * w1.x; acc[2][5] += a2 * w1.y; acc[2][6] += a2 * w1.z; acc[2][7] += a2 * w1.w;
        acc[3][0] += a3 * w0.x; acc[3][1] += a3 * w0.y; acc[3][2] += a3 * w0.z; acc[3][3] += a3 * w0.w;
        acc[3][4] += a3 * w1.x; acc[3][5] += a3 * w1.y; acc[3][6] += a3 * w1.z; acc[3][7] += a3 * w1.w;
    }

    float4 b0 = *(const float4*)(bias + cg * 8);
    float4 b1 = *(const float4*)(bias + cg * 8 + 4);
    float bb[8] = { b0.x, b0.y, b0.z, b0.w, b1.x, b1.y, b1.z, b1.w };

#pragma unroll
    for (int i = 0; i < 4; i++) {
        int grow = row0 + rg * 4 + i;
        int b = grow / NN;
        int r = grow - b * NN;
        float d = deg[grow];
        float sc = 1.0f / fmaxf(d, 1.0f);
        bool alive = r < num_nodes[b];
        float o[8];
#pragma unroll
        for (int j = 0; j < 8; j++)
            o[j] = alive ? (acc[i][j] + d * bb[j]) * sc : 0.0f;
        float* dst = io + (size_t)grow * CC + cg * 8;
        *(float4*)(dst)     = make_float4(o[0], o[1], o[2], o[3]);
        *(float4*)(dst + 4) = make_float4(o[4], o[5], o[6], o[7]);
    }
}

extern "C" void kernel_launch(void* const* d_in, const int* in_sizes, int n_in,
                              void* d_out, int out_size, void* d_ws, size_t ws_size,
                              hipStream_t stream) {
    const float* x        = (const float*)d_in[0];
    const float* weight   = (const float*)d_in[1];
    const float* bias     = (const float*)d_in[2];
    const int*   edge_row = (const int*)d_in[3];
    const int*   edge_col = (const int*)d_in[4];
    const float* edge_val = (const float*)d_in[5];
    const int*   num_nodes= (const int*)d_in[6];
    float* out = (float*)d_out;

    int2*  binned  = (int2*)d_out;                      // phase-A scratch in d_out
    int2*  sorted  = (int2*)d_ws;                       // BE int2
    float* deg     = (float*)d_ws + 2 * (size_t)BE;     // BN f32
    int*   row_off = (int*)d_ws + 2 * (size_t)BE + BN;  // BN int
    int*   row_cnt = row_off + BN;                      // BN int
    int*   counts  = row_cnt + BN;                      // 800
    int*   offsets = counts + BG * NBKT;
    int*   gcursor = offsets + BG * NBKT;

    hipMemsetAsync(counts, 0, BG * NBKT * sizeof(int), stream);
    k_bhist<<<BG * BPG, 256, 0, stream>>>(edge_row, counts);
    k_scan<<<1, 1024, 0, stream>>>(counts, offsets, gcursor);
    k_bin<<<BG * BPG, 256, 0, stream>>>(edge_row, edge_col, edge_val, gcursor, binned);
    k_sort<<<BG * NBKT, 256, 0, stream>>>(binned, offsets, counts, sorted,
                                          row_off, row_cnt);
    k_gather<<<8 * (NN / 4), 256, 0, stream>>>(x, row_off, row_cnt, sorted, out, deg);
    k_gemm<<<BN / 64, 256, 0, stream>>>(out, weight, bias, deg, num_nodes);
}

// Round 6
// 317.729 us; speedup vs baseline: 7.5148x; 1.2169x over previous
//
#include <hip/hip_runtime.h>

// Problem constants (match reference)
#define BG   8          // graphs
#define NN   10000      // nodes per graph
#define EE   320000     // edges per graph
#define CC   128        // channels (in == out)
#define BN   (BG*NN)    // 80000
#define BE   (BG*EE)    // 2560000

#define NBKT   100      // buckets per graph (100 rows each)
#define BROWS  100      // rows per bucket
#define CHUNK  4096     // edges per binning block
#define BPG    ((EE + CHUNK - 1) / CHUNK)   // 79 blocks per graph

// bucket(row) = floor(row/100) via multiply-shift (exact for row < 10486)
__device__ __forceinline__ int bucket_of(int r) { return (r * 5243) >> 19; }

// ---------------------------------------------------------------------------
// Buffers:
//   d_out (41 MB) doubles as the phase-A "binned" buffer (BE int2 = 20.5 MB),
//   consumed by k_sort before k_gather overwrites d_out with aggx.
// Workspace layout:
//   [0, BE) int2            sorted edges {col, val_bits}, row-sorted per graph
//   then deg      (BN f32)   computed in k_sort
//   then row_off  (BN int)
//   then row_cnt  (BN int)
//   then counts   (800 int)  bucket counts   <- memset 0 each call
//   then offsets  (800 int)
//   then gcursor  (800 int)
// total ~21.5 MB
// ---------------------------------------------------------------------------

__global__ __launch_bounds__(256) void k_bhist(const int* __restrict__ edge_row,
                                               int* __restrict__ counts) {
    int g = blockIdx.x / BPG;
    int cstart = (blockIdx.x % BPG) * CHUNK;
    int t = threadIdx.x;
    __shared__ int lh[NBKT];
    if (t < NBKT) lh[t] = 0;
    __syncthreads();
#pragma unroll
    for (int j = 0; j < CHUNK / 256; j++) {
        int e = cstart + j * 256 + t;
        if (e < EE) {
            int r = edge_row[(size_t)g * EE + e];
            atomicAdd(&lh[bucket_of(r)], 1);
        }
    }
    __syncthreads();
    if (t < NBKT && lh[t]) atomicAdd(&counts[g * NBKT + t], lh[t]);
}

// exclusive scan of bucket counts per graph (8 x 100); one block.
__global__ __launch_bounds__(1024) void k_scan(const int* __restrict__ counts,
                                               int* __restrict__ offsets,
                                               int* __restrict__ gcursor) {
    __shared__ int s[1024];
    int t = threadIdx.x;
    int g = t >> 7, i = t & 127;
    int own = (i < NBKT) ? counts[g * NBKT + i] : 0;
    s[t] = own;
    __syncthreads();
#pragma unroll
    for (int d = 1; d < 128; d <<= 1) {
        int add = (i >= d) ? s[t - d] : 0;
        __syncthreads();
        s[t] += add;
        __syncthreads();
    }
    if (i < NBKT) {
        int ex = s[t] - own;
        offsets[g * NBKT + i] = ex;
        gcursor[g * NBKT + i] = ex;
    }
}

__global__ __launch_bounds__(256) void k_bin(const int* __restrict__ edge_row,
                                             const int* __restrict__ edge_col,
                                             const float* __restrict__ edge_val,
                                             int* __restrict__ gcursor,
                                             int2* __restrict__ binned) {
    int g = blockIdx.x / BPG;
    int cstart = (blockIdx.x % BPG) * CHUNK;
    int t = threadIdx.x;
    __shared__ int lh[NBKT];
    __shared__ int lbase[NBKT];
    if (t < NBKT) lh[t] = 0;
    __syncthreads();
    int rows[CHUNK / 256];
#pragma unroll
    for (int j = 0; j < CHUNK / 256; j++) {
        int e = cstart + j * 256 + t;
        if (e < EE) {
            int r = edge_row[(size_t)g * EE + e];
            rows[j] = r;
            atomicAdd(&lh[bucket_of(r)], 1);
        } else rows[j] = -1;
    }
    __syncthreads();
    if (t < NBKT) lbase[t] = lh[t] ? atomicAdd(&gcursor[g * NBKT + t], lh[t]) : 0;
    __syncthreads();
    if (t < NBKT) lh[t] = 0;
    __syncthreads();
#pragma unroll
    for (int j = 0; j < CHUNK / 256; j++) {
        if (rows[j] >= 0) {
            int e = cstart + j * 256 + t;
            int r = rows[j];
            int bin = bucket_of(r);
            int pos = lbase[bin] + atomicAdd(&lh[bin], 1);
            int col = edge_col[(size_t)g * EE + e];
            float v = edge_val[(size_t)g * EE + e];
            binned[(size_t)g * EE + pos] =
                make_int2(((r - bin * BROWS) << 14) | col, __float_as_int(v));
        }
    }
}

// One block per (graph, bucket): counting-sort the bucket's edges by row.
// Also computes deg (row-sum of vals). Emits {col,val} pairs + row offsets.
__global__ __launch_bounds__(256) void k_sort(const int2* __restrict__ binned,
                                              const int* __restrict__ boff,
                                              const int* __restrict__ bcnt,
                                              int2* __restrict__ sorted,
                                              int* __restrict__ row_off,
                                              int* __restrict__ row_cnt,
                                              float* __restrict__ deg) {
    int g = blockIdx.x / NBKT;
    int bkt = blockIdx.x % NBKT;
    int t = threadIdx.x;
    __shared__ int cnts[BROWS], excl[BROWS], curs[BROWS];
    __shared__ float degl[BROWS];
    if (t < BROWS) { cnts[t] = 0; degl[t] = 0.f; }
    __syncthreads();
    int start = boff[g * NBKT + bkt];
    int cnt = bcnt[g * NBKT + bkt];
    const int2* src = binned + (size_t)g * EE + start;
    for (int i = t; i < cnt; i += 256) {
        int2 ed = src[i];
        atomicAdd(&cnts[ed.x >> 14], 1);
        atomicAdd(&degl[ed.x >> 14], __int_as_float(ed.y));
    }
    __syncthreads();
    if (t == 0) {
        int a = 0;
        for (int i = 0; i < BROWS; i++) { excl[i] = a; a += cnts[i]; }
    }
    __syncthreads();
    if (t < BROWS) {
        curs[t] = excl[t];
        int row = g * NN + bkt * BROWS + t;
        row_off[row] = start + excl[t];
        row_cnt[row] = cnts[t];
        deg[row] = degl[t];
    }
    __syncthreads();
    int2* dst = sorted + (size_t)g * EE + start;
    for (int i = t; i < cnt; i += 256) {
        int2 ed = src[i];
        int pos = atomicAdd(&curs[ed.x >> 14], 1);
        dst[pos] = make_int2(ed.x & 0x3FFF, ed.y);
    }
}

// One wave per row. Wave-uniform meta via readfirstlane -> SALU address calc
// (SADDR global loads), SGPR val operand to v_fma. Per-edge VALU ~= 2 FMA.
__global__ __launch_bounds__(256) void k_gather(const float* __restrict__ x,
                                                const int* __restrict__ row_off,
                                                const int* __restrict__ row_cnt,
                                                const int2* __restrict__ sorted,
                                                float* __restrict__ aggx) {
    int bid = blockIdx.x;
    int g = bid & 7;                          // graph -> XCD L2 affinity
    int chunk = bid >> 3;
    int wid = threadIdx.x >> 6, lane = threadIdx.x & 63;
    int r = chunk * 4 + wid;
    int bn = g * NN + r;
    int start = __builtin_amdgcn_readfirstlane(row_off[bn]);
    int cnt = __builtin_amdgcn_readfirstlane(row_cnt[bn]);
    const float* xb = x + (size_t)g * NN * CC + 2 * lane;
    const int2* ep = sorted + (size_t)g * EE + start;

    float2 a0 = make_float2(0.f, 0.f), a1 = make_float2(0.f, 0.f);
    int e = 0;
    for (; e + 8 <= cnt; e += 8) {
        int c[8]; float v[8];
#pragma unroll
        for (int j = 0; j < 8; j++) {
            int2 m = ep[e + j];
            c[j] = __builtin_amdgcn_readfirstlane(m.x);
            v[j] = __int_as_float(__builtin_amdgcn_readfirstlane(m.y));
        }
        float2 xv[8];
#pragma unroll
        for (int j = 0; j < 8; j++)
            xv[j] = *(const float2*)(xb + ((size_t)c[j] << 7));
#pragma unroll
        for (int j = 0; j < 8; j++) {
            if (j & 1) { a1.x += v[j] * xv[j].x; a1.y += v[j] * xv[j].y; }
            else       { a0.x += v[j] * xv[j].x; a0.y += v[j] * xv[j].y; }
        }
    }
    for (; e < cnt; e++) {
        int2 m = ep[e];
        int c0 = __builtin_amdgcn_readfirstlane(m.x);
        float v0 = __int_as_float(__builtin_amdgcn_readfirstlane(m.y));
        float2 xv = *(const float2*)(xb + ((size_t)c0 << 7));
        a0.x += v0 * xv.x; a0.y += v0 * xv.y;
    }
    float2 res = make_float2(a0.x + a1.x, a0.y + a1.y);
    *(float2*)(aggx + (size_t)bn * CC + 2 * lane) = res;
}

// out[row] = mask * (aggx[row] @ W + deg*bias) / max(deg,1)
__global__ __launch_bounds__(256) void k_gemm(float* __restrict__ io,
                                              const float* __restrict__ W,
                                              const float* __restrict__ bias,
                                              const float* __restrict__ deg,
                                              const int* __restrict__ num_nodes) {
    __shared__ float at[64][132];
    int t = threadIdx.x;
    int row0 = blockIdx.x * 64;

    const float4* src = (const float4*)(io + (size_t)row0 * CC);
#pragma unroll
    for (int i = 0; i < 8; i++) {
        int f4 = t + i * 256;
        float4 v = src[f4];
        int row = f4 >> 5;
        int col4 = f4 & 31;
        *(float4*)(&at[row][col4 * 4]) = v;
    }
    __syncthreads();

    int cg = t & 15;
    int rg = t >> 4;
    float acc[4][8] = {};
#pragma unroll 4
    for (int k = 0; k < 128; k++) {
        float4 w0 = *(const float4*)(W + k * 128 + cg * 8);
        float4 w1 = *(const float4*)(W + k * 128 + cg * 8 + 4);
        float a0 = at[rg * 4 + 0][k];
        float a1 = at[rg * 4 + 1][k];
        float a2 = at[rg * 4 + 2][k];
        float a3 = at[rg * 4 + 3][k];
        acc[0][0] += a0 * w0.x; acc[0][1] += a0 * w0.y; acc[0][2] += a0 * w0.z; acc[0][3] += a0 * w0.w;
        acc[0][4] += a0 * w1.x; acc[0][5] += a0 * w1.y; acc[0][6] += a0 * w1.z; acc[0][7] += a0 * w1.w;
        acc[1][0] += a1 * w0.x; acc[1][1] += a1 * w0.y; acc[1][2] += a1 * w0.z; acc[1][3] += a1 * w0.w;
        acc[1][4] += a1 * w1.x; acc[1][5] += a1 * w1.y; acc[1][6] += a1 * w1.z; acc[1][7] += a1 * w1.w;
        acc[2][0] += a2 * w0.x; acc[2][1] += a2 * w0.y; acc[2][2] += a2 * w0.z; acc[2][3] += a2 * w0.w;
        acc[2][4] += a2 * w1.x; acc[2][5] += a2 * w1.y; acc[2][6] += a2 * w1.z; acc[2][7] += a2 * w1.w;
        acc[3][0] += a3 * w0.x; acc[3][1] += a3 * w0.y; acc[3][2] += a3 * w0.z; acc[3][3] += a3 * w0.w;
        acc[3][4] += a3 * w1.x; acc[3][5] += a3 * w1.y; acc[3][6] += a3 * w1.z; acc[3][7] += a3 * w1.w;
    }

    float4 b0 = *(const float4*)(bias + cg * 8);
    float4 b1 = *(const float4*)(bias + cg * 8 + 4);
    float bb[8] = { b0.x, b0.y, b0.z, b0.w, b1.x, b1.y, b1.z, b1.w };

#pragma unroll
    for (int i = 0; i < 4; i++) {
        int grow = row0 + rg * 4 + i;
        int b = grow / NN;
        int r = grow - b * NN;
        float d = deg[grow];
        float sc = 1.0f / fmaxf(d, 1.0f);
        bool alive = r < num_nodes[b];
        float o[8];
#pragma unroll
        for (int j = 0; j < 8; j++)
            o[j] = alive ? (acc[i][j] + d * bb[j]) * sc : 0.0f;
        float* dst = io + (size_t)grow * CC + cg * 8;
        *(float4*)(dst)     = make_float4(o[0], o[1], o[2], o[3]);
        *(float4*)(dst + 4) = make_float4(o[4], o[5], o[6], o[7]);
    }
}

extern "C" void kernel_launch(void* const* d_in, const int* in_sizes, int n_in,
                              void* d_out, int out_size, void* d_ws, size_t ws_size,
                              hipStream_t stream) {
    const float* x        = (const float*)d_in[0];
    const float* weight   = (const float*)d_in[1];
    const float* bias     = (const float*)d_in[2];
    const int*   edge_row = (const int*)d_in[3];
    const int*   edge_col = (const int*)d_in[4];
    const float* edge_val = (const float*)d_in[5];
    const int*   num_nodes= (const int*)d_in[6];
    float* out = (float*)d_out;

    int2*  binned  = (int2*)d_out;                      // phase-A scratch in d_out
    int2*  sorted  = (int2*)d_ws;                       // BE int2
    float* deg     = (float*)d_ws + 2 * (size_t)BE;     // BN f32
    int*   row_off = (int*)d_ws + 2 * (size_t)BE + BN;  // BN int
    int*   row_cnt = row_off + BN;                      // BN int
    int*   counts  = row_cnt + BN;                      // 800
    int*   offsets = counts + BG * NBKT;
    int*   gcursor = offsets + BG * NBKT;

    hipMemsetAsync(counts, 0, BG * NBKT * sizeof(int), stream);
    k_bhist<<<BG * BPG, 256, 0, stream>>>(edge_row, counts);
    k_scan<<<1, 1024, 0, stream>>>(counts, offsets, gcursor);
    k_bin<<<BG * BPG, 256, 0, stream>>>(edge_row, edge_col, edge_val, gcursor, binned);
    k_sort<<<BG * NBKT, 256, 0, stream>>>(binned, offsets, counts, sorted,
                                          row_off, row_cnt, deg);
    k_gather<<<8 * (NN / 4), 256, 0, stream>>>(x, row_off, row_cnt, sorted, out);
    k_gemm<<<BN / 64, 256, 0, stream>>>(out, weight, bias, deg, num_nodes);
}

// Round 7
// 305.017 us; speedup vs baseline: 7.8280x; 1.0417x over previous
//
#include <hip/hip_runtime.h>

// Problem constants (match reference)
#define BG   8          // graphs
#define NN   10000      // nodes per graph
#define EE   320000     // edges per graph
#define CC   128        // channels (in == out)
#define BN   (BG*NN)    // 80000
#define BE   (BG*EE)    // 2560000

#define NBKT   157      // buckets per graph: ceil(10000/64), bkt = row >> 6
#define BROWS  64       // rows per bucket, row_local = row & 63
#define CAP    2560     // slots per bucket (mean 2048, sd ~45 -> 11 sigma)
#define CHUNK  4096     // edges per binning block
#define BPG    ((EE + CHUNK - 1) / CHUNK)   // 79 blocks per graph

// ---------------------------------------------------------------------------
// Buffers:
//   d_out (41 MB) doubles as the capacity-strided "binned" buffer
//   (BG*NBKT*CAP int2 = 25.7 MB), consumed by k_sort before k_gather
//   overwrites d_out with aggx.
// Workspace:
//   sorted   BG*NBKT*CAP int2 (25.7 MB)  row-sorted {col, val_bits}
//   deg      BN f32
//   row_off  BN int   (graph-local index into capacity-strided sorted)
//   row_cnt  BN int
//   cursor   BG*NBKT int   <- memset 0 each call
// total ~26.7 MB
// ---------------------------------------------------------------------------

__global__ __launch_bounds__(256) void k_bin(const int* __restrict__ edge_row,
                                             const int* __restrict__ edge_col,
                                             const float* __restrict__ edge_val,
                                             int* __restrict__ cursor,
                                             int2* __restrict__ binned) {
    int g = blockIdx.x / BPG;
    int cstart = (blockIdx.x % BPG) * CHUNK;
    int t = threadIdx.x;
    __shared__ int lh[NBKT];
    __shared__ int lbase[NBKT];
    for (int i = t; i < NBKT; i += 256) lh[i] = 0;
    __syncthreads();
    int rows[CHUNK / 256];
#pragma unroll
    for (int j = 0; j < CHUNK / 256; j++) {
        int e = cstart + j * 256 + t;
        if (e < EE) {
            int r = edge_row[(size_t)g * EE + e];
            rows[j] = r;
            atomicAdd(&lh[r >> 6], 1);
        } else rows[j] = -1;
    }
    __syncthreads();
    for (int i = t; i < NBKT; i += 256) {
        int c = lh[i];
        lbase[i] = c ? atomicAdd(&cursor[g * NBKT + i], c) : 0;
        lh[i] = 0;
    }
    __syncthreads();
#pragma unroll
    for (int j = 0; j < CHUNK / 256; j++) {
        if (rows[j] >= 0) {
            int e = cstart + j * 256 + t;
            int r = rows[j];
            int bkt = r >> 6;
            int pos = lbase[bkt] + atomicAdd(&lh[bkt], 1);
            binned[((size_t)g * NBKT + bkt) * CAP + pos] =
                make_int2(((r & 63) << 14) | edge_col[(size_t)g * EE + e],
                          __float_as_int(edge_val[(size_t)g * EE + e]));
        }
    }
}

// One block per (graph, bucket): LDS-resident counting sort by row_local.
// Coalesced read, LDS scatter, coalesced write. Emits row_off/cnt/deg.
__global__ __launch_bounds__(256) void k_sort(const int2* __restrict__ binned,
                                              const int* __restrict__ bcnt,
                                              int2* __restrict__ sorted,
                                              int* __restrict__ row_off,
                                              int* __restrict__ row_cnt,
                                              float* __restrict__ deg) {
    int g = blockIdx.x / NBKT;
    int bkt = blockIdx.x % NBKT;
    int t = threadIdx.x;
    __shared__ int2 ein[CAP];      // 20.5 KB
    __shared__ int2 eout[CAP];     // 20.5 KB
    __shared__ int cnts[BROWS], excl[BROWS], curs[BROWS];
    __shared__ float degl[BROWS];
    if (t < BROWS) { cnts[t] = 0; degl[t] = 0.f; }
    __syncthreads();
    int cnt = bcnt[g * NBKT + bkt];
    if (cnt > CAP) cnt = CAP;      // statistically impossible; memory safety
    const int2* src = binned + ((size_t)g * NBKT + bkt) * CAP;
    for (int i = t; i < cnt; i += 256) {
        int2 ed = src[i];
        ein[i] = ed;
        atomicAdd(&cnts[ed.x >> 14], 1);
        atomicAdd(&degl[ed.x >> 14], __int_as_float(ed.y));
    }
    __syncthreads();
    if (t < 64) {                  // wave 0: exclusive scan of 64 counts
        int own = cnts[t];
        int v = own;
#pragma unroll
        for (int d = 1; d < 64; d <<= 1) {
            int n = __shfl_up(v, d);
            if (t >= d) v += n;
        }
        excl[t] = v - own;
        curs[t] = v - own;
        int gr = bkt * BROWS + t;
        if (gr < NN) {
            int row = g * NN + gr;
            row_off[row] = bkt * CAP + (v - own);
            row_cnt[row] = own;
            deg[row] = degl[t];
        }
    }
    __syncthreads();
    for (int i = t; i < cnt; i += 256) {
        int2 ed = ein[i];
        int pos = atomicAdd(&curs[ed.x >> 14], 1);
        eout[pos] = make_int2(ed.x & 0x3FFF, ed.y);
    }
    __syncthreads();
    int2* dst = sorted + ((size_t)g * NBKT + bkt) * CAP;
    for (int i = t; i < cnt; i += 256) dst[i] = eout[i];
}

// One wave per row, one channel-half per pass (64 ch, lane owns 1 channel).
// Per-pass x working set = 2.56 MB/graph -> XCD-L2-resident (bid&7 = graph).
// Meta via nontemporal uniform loads + readfirstlane (SALU addressing);
// aggx written nontemporal to avoid evicting x from L2.
__global__ __launch_bounds__(256) void k_gather(const float* __restrict__ x,
                                                const int* __restrict__ row_off,
                                                const int* __restrict__ row_cnt,
                                                const int2* __restrict__ sorted,
                                                float* __restrict__ aggx,
                                                int pass) {
    int bid = blockIdx.x;
    int g = bid & 7;
    int chunk = bid >> 3;
    int wid = threadIdx.x >> 6, lane = threadIdx.x & 63;
    int r = chunk * 4 + wid;
    int bn = g * NN + r;
    int start = __builtin_amdgcn_readfirstlane(row_off[bn]);
    int cnt = __builtin_amdgcn_readfirstlane(row_cnt[bn]);
    const float* xb = x + (size_t)g * NN * CC + pass * 64 + lane;
    const long long* ep =
        (const long long*)(sorted + (size_t)g * NBKT * CAP + start);

    float a0 = 0.f, a1 = 0.f;
    int e = 0;
    for (; e + 8 <= cnt; e += 8) {
        int c[8]; float v[8];
#pragma unroll
        for (int j = 0; j < 8; j++) {
            long long m = __builtin_nontemporal_load(ep + e + j);
            c[j] = __builtin_amdgcn_readfirstlane((int)m);
            v[j] = __int_as_float(__builtin_amdgcn_readfirstlane((int)(m >> 32)));
        }
        float xv[8];
#pragma unroll
        for (int j = 0; j < 8; j++)
            xv[j] = xb[(size_t)c[j] << 7];
#pragma unroll
        for (int j = 0; j < 8; j++) {
            if (j & 1) a1 += v[j] * xv[j];
            else       a0 += v[j] * xv[j];
        }
    }
    for (; e < cnt; e++) {
        long long m = __builtin_nontemporal_load(ep + e);
        int c0 = __builtin_amdgcn_readfirstlane((int)m);
        float v0 = __int_as_float(__builtin_amdgcn_readfirstlane((int)(m >> 32)));
        a0 += v0 * xb[(size_t)c0 << 7];
    }
    __builtin_nontemporal_store(a0 + a1,
                                aggx + (size_t)bn * CC + pass * 64 + lane);
}

// out[row] = mask * (aggx[row] @ W + deg*bias) / max(deg,1)
__global__ __launch_bounds__(256) void k_gemm(float* __restrict__ io,
                                              const float* __restrict__ W,
                                              const float* __restrict__ bias,
                                              const float* __restrict__ deg,
                                              const int* __restrict__ num_nodes) {
    __shared__ float at[64][132];
    int t = threadIdx.x;
    int row0 = blockIdx.x * 64;

    const float4* src = (const float4*)(io + (size_t)row0 * CC);
#pragma unroll
    for (int i = 0; i < 8; i++) {
        int f4 = t + i * 256;
        float4 v = src[f4];
        int row = f4 >> 5;
        int col4 = f4 & 31;
        *(float4*)(&at[row][col4 * 4]) = v;
    }
    __syncthreads();

    int cg = t & 15;
    int rg = t >> 4;
    float acc[4][8] = {};
#pragma unroll 4
    for (int k = 0; k < 128; k++) {
        float4 w0 = *(const float4*)(W + k * 128 + cg * 8);
        float4 w1 = *(const float4*)(W + k * 128 + cg * 8 + 4);
        float a0 = at[rg * 4 + 0][k];
        float a1 = at[rg * 4 + 1][k];
        float a2 = at[rg * 4 + 2][k];
        float a3 = at[rg * 4 + 3][k];
        acc[0][0] += a0 * w0.x; acc[0][1] += a0 * w0.y; acc[0][2] += a0 * w0.z; acc[0][3] += a0 * w0.w;
        acc[0][4] += a0 * w1.x; acc[0][5] += a0 * w1.y; acc[0][6] += a0 * w1.z; acc[0][7] += a0 * w1.w;
        acc[1][0] += a1 * w0.x; acc[1][1] += a1 * w0.y; acc[1][2] += a1 * w0.z; acc[1][3] += a1 * w0.w;
        acc[1][4] += a1 * w1.x; acc[1][5] += a1 * w1.y; acc[1][6] += a1 * w1.z; acc[1][7] += a1 * w1.w;
        acc[2][0] += a2 * w0.x; acc[2][1] += a2 * w0.y; acc[2][2] += a2 * w0.z; acc[2][3] += a2 * w0.w;
        acc[2][4] += a2 * w1.x; acc[2][5] += a2 * w1.y; acc[2][6] += a2 * w1.z; acc[2][7] += a2 * w1.w;
        acc[3][0] += a3 * w0.x; acc[3][1] += a3 * w0.y; acc[3][2] += a3 * w0.z; acc[3][3] += a3 * w0.w;
        acc[3][4] += a3 * w1.x; acc[3][5] += a3 * w1.y; acc[3][6] += a3 * w1.z; acc[3][7] += a3 * w1.w;
    }

    float4 b0 = *(const float4*)(bias + cg * 8);
    float4 b1 = *(const float4*)(bias + cg * 8 + 4);
    float bb[8] = { b0.x, b0.y, b0.z, b0.w, b1.x, b1.y, b1.z, b1.w };

#pragma unroll
    for (int i = 0; i < 4; i++) {
        int grow = row0 + rg * 4 + i;
        int b = grow / NN;
        int r = grow - b * NN;
        float d = deg[grow];
        float sc = 1.0f / fmaxf(d, 1.0f);
        bool alive = r < num_nodes[b];
        float o[8];
#pragma unroll
        for (int j = 0; j < 8; j++)
            o[j] = alive ? (acc[i][j] + d * bb[j]) * sc : 0.0f;
        float* dst = io + (size_t)grow * CC + cg * 8;
        *(float4*)(dst)     = make_float4(o[0], o[1], o[2], o[3]);
        *(float4*)(dst + 4) = make_float4(o[4], o[5], o[6], o[7]);
    }
}

extern "C" void kernel_launch(void* const* d_in, const int* in_sizes, int n_in,
                              void* d_out, int out_size, void* d_ws, size_t ws_size,
                              hipStream_t stream) {
    const float* x        = (const float*)d_in[0];
    const float* weight   = (const float*)d_in[1];
    const float* bias     = (const float*)d_in[2];
    const int*   edge_row = (const int*)d_in[3];
    const int*   edge_col = (const int*)d_in[4];
    const float* edge_val = (const float*)d_in[5];
    const int*   num_nodes= (const int*)d_in[6];
    float* out = (float*)d_out;

    int2*  binned  = (int2*)d_out;                      // phase-A scratch in d_out
    int2*  sorted  = (int2*)d_ws;                       // BG*NBKT*CAP int2
    float* deg     = (float*)(sorted + (size_t)BG * NBKT * CAP);
    int*   row_off = (int*)(deg + BN);
    int*   row_cnt = row_off + BN;
    int*   cursor  = row_cnt + BN;                      // BG*NBKT ints

    hipMemsetAsync(cursor, 0, BG * NBKT * sizeof(int), stream);
    k_bin<<<BG * BPG, 256, 0, stream>>>(edge_row, edge_col, edge_val, cursor, binned);
    k_sort<<<BG * NBKT, 256, 0, stream>>>(binned, cursor, sorted,
                                          row_off, row_cnt, deg);
    k_gather<<<8 * (NN / 4), 256, 0, stream>>>(x, row_off, row_cnt, sorted, out, 0);
    k_gather<<<8 * (NN / 4), 256, 0, stream>>>(x, row_off, row_cnt, sorted, out, 1);
    k_gemm<<<BN / 64, 256, 0, stream>>>(out, weight, bias, deg, num_nodes);
}

// Round 8
// 295.631 us; speedup vs baseline: 8.0765x; 1.0317x over previous
//
#include <hip/hip_runtime.h>

// Problem constants (match reference)
#define BG   8          // graphs
#define NN   10000      // nodes per graph
#define EE   320000     // edges per graph
#define CC   128        // channels (in == out)
#define BN   (BG*NN)    // 80000
#define BE   (BG*EE)    // 2560000

#define NBKT   157      // buckets per graph: ceil(10000/64), bkt = row >> 6
#define BROWS  64       // rows per bucket, row_local = row & 63
#define CAP    2560     // slots per bucket (mean 2048, sd ~45 -> 11 sigma)
#define CHUNK  4096     // edges per binning block
#define BPG    ((EE + CHUNK - 1) / CHUNK)   // 79 blocks per graph

// ---------------------------------------------------------------------------
// Buffers:
//   d_out (41 MB) doubles as the capacity-strided "binned" buffer
//   (BG*NBKT*CAP int2 = 25.7 MB), consumed by k_sort before k_gather
//   overwrites d_out with aggx.
// Workspace:
//   sorted   BG*NBKT*CAP int2 (25.7 MB)  row-sorted {col, val_bits}
//   deg      BN f32
//   row_off  BN int   (graph-local index into capacity-strided sorted)
//   row_cnt  BN int
//   cursor   BG*NBKT int   <- memset 0 each call
// total ~26.7 MB
// ---------------------------------------------------------------------------

__global__ __launch_bounds__(256) void k_bin(const int* __restrict__ edge_row,
                                             const int* __restrict__ edge_col,
                                             const float* __restrict__ edge_val,
                                             int* __restrict__ cursor,
                                             int2* __restrict__ binned) {
    int g = blockIdx.x / BPG;
    int cstart = (blockIdx.x % BPG) * CHUNK;
    int t = threadIdx.x;
    __shared__ int lh[NBKT];
    __shared__ int lbase[NBKT];
    for (int i = t; i < NBKT; i += 256) lh[i] = 0;
    __syncthreads();
    int rows[CHUNK / 256];
#pragma unroll
    for (int j = 0; j < CHUNK / 256; j++) {
        int e = cstart + j * 256 + t;
        if (e < EE) {
            int r = edge_row[(size_t)g * EE + e];
            rows[j] = r;
            atomicAdd(&lh[r >> 6], 1);
        } else rows[j] = -1;
    }
    __syncthreads();
    for (int i = t; i < NBKT; i += 256) {
        int c = lh[i];
        lbase[i] = c ? atomicAdd(&cursor[g * NBKT + i], c) : 0;
        lh[i] = 0;
    }
    __syncthreads();
#pragma unroll
    for (int j = 0; j < CHUNK / 256; j++) {
        if (rows[j] >= 0) {
            int e = cstart + j * 256 + t;
            int r = rows[j];
            int bkt = r >> 6;
            int pos = lbase[bkt] + atomicAdd(&lh[bkt], 1);
            binned[((size_t)g * NBKT + bkt) * CAP + pos] =
                make_int2(((r & 63) << 14) | edge_col[(size_t)g * EE + e],
                          __float_as_int(edge_val[(size_t)g * EE + e]));
        }
    }
}

// One block per (graph, bucket): LDS-resident counting sort by row_local.
// Coalesced read, LDS scatter, coalesced write. Emits row_off/cnt/deg.
__global__ __launch_bounds__(256) void k_sort(const int2* __restrict__ binned,
                                              const int* __restrict__ bcnt,
                                              int2* __restrict__ sorted,
                                              int* __restrict__ row_off,
                                              int* __restrict__ row_cnt,
                                              float* __restrict__ deg) {
    int g = blockIdx.x / NBKT;
    int bkt = blockIdx.x % NBKT;
    int t = threadIdx.x;
    __shared__ int2 ein[CAP];      // 20.5 KB
    __shared__ int2 eout[CAP];     // 20.5 KB
    __shared__ int cnts[BROWS], excl[BROWS], curs[BROWS];
    __shared__ float degl[BROWS];
    if (t < BROWS) { cnts[t] = 0; degl[t] = 0.f; }
    __syncthreads();
    int cnt = bcnt[g * NBKT + bkt];
    if (cnt > CAP) cnt = CAP;      // statistically impossible; memory safety
    const int2* src = binned + ((size_t)g * NBKT + bkt) * CAP;
    for (int i = t; i < cnt; i += 256) {
        int2 ed = src[i];
        ein[i] = ed;
        atomicAdd(&cnts[ed.x >> 14], 1);
        atomicAdd(&degl[ed.x >> 14], __int_as_float(ed.y));
    }
    __syncthreads();
    if (t < 64) {                  // wave 0: exclusive scan of 64 counts
        int own = cnts[t];
        int v = own;
#pragma unroll
        for (int d = 1; d < 64; d <<= 1) {
            int n = __shfl_up(v, d);
            if (t >= d) v += n;
        }
        excl[t] = v - own;
        curs[t] = v - own;
        int gr = bkt * BROWS + t;
        if (gr < NN) {
            int row = g * NN + gr;
            row_off[row] = bkt * CAP + (v - own);
            row_cnt[row] = own;
            deg[row] = degl[t];
        }
    }
    __syncthreads();
    for (int i = t; i < cnt; i += 256) {
        int2 ed = ein[i];
        int pos = atomicAdd(&curs[ed.x >> 14], 1);
        eout[pos] = make_int2(ed.x & 0x3FFF, ed.y);
    }
    __syncthreads();
    int2* dst = sorted + ((size_t)g * NBKT + bkt) * CAP;
    for (int i = t; i < cnt; i += 256) dst[i] = eout[i];
}

// One wave per row, one channel-half per pass (64 ch, lane owns 1 channel).
// Per-pass x working set = 2.56 MB/graph -> XCD-L2-resident (bid&7 = graph).
// Meta via nontemporal uniform loads + readfirstlane (SALU addressing);
// aggx written nontemporal to avoid evicting x from L2.
__global__ __launch_bounds__(256) void k_gather(const float* __restrict__ x,
                                                const int* __restrict__ row_off,
                                                const int* __restrict__ row_cnt,
                                                const int2* __restrict__ sorted,
                                                float* __restrict__ aggx,
                                                int pass) {
    int bid = blockIdx.x;
    int g = bid & 7;
    int chunk = bid >> 3;
    int wid = threadIdx.x >> 6, lane = threadIdx.x & 63;
    int r = chunk * 4 + wid;
    int bn = g * NN + r;
    int start = __builtin_amdgcn_readfirstlane(row_off[bn]);
    int cnt = __builtin_amdgcn_readfirstlane(row_cnt[bn]);
    const float* xb = x + (size_t)g * NN * CC + pass * 64 + lane;
    const long long* ep =
        (const long long*)(sorted + (size_t)g * NBKT * CAP + start);

    float a0 = 0.f, a1 = 0.f;
    int e = 0;
    for (; e + 8 <= cnt; e += 8) {
        int c[8]; float v[8];
#pragma unroll
        for (int j = 0; j < 8; j++) {
            long long m = __builtin_nontemporal_load(ep + e + j);
            c[j] = __builtin_amdgcn_readfirstlane((int)m);
            v[j] = __int_as_float(__builtin_amdgcn_readfirstlane((int)(m >> 32)));
        }
        float xv[8];
#pragma unroll
        for (int j = 0; j < 8; j++)
            xv[j] = xb[(size_t)c[j] << 7];
#pragma unroll
        for (int j = 0; j < 8; j++) {
            if (j & 1) a1 += v[j] * xv[j];
            else       a0 += v[j] * xv[j];
        }
    }
    for (; e < cnt; e++) {
        long long m = __builtin_nontemporal_load(ep + e);
        int c0 = __builtin_amdgcn_readfirstlane((int)m);
        float v0 = __int_as_float(__builtin_amdgcn_readfirstlane((int)(m >> 32)));
        a0 += v0 * xb[(size_t)c0 << 7];
    }
    __builtin_nontemporal_store(a0 + a1,
                                aggx + (size_t)bn * CC + pass * 64 + lane);
}

// out[row] = mask * (aggx[row] @ W + deg*bias) / max(deg,1)
// W staged fully in LDS (64 KB -> 2 blocks/CU); a-rows read directly from
// global as float4 (broadcast across the 16 lanes sharing a row).
// Inner loop per 4-k chunk: 4 global float4 + 8 ds_read_b128 + 128 FMA.
__global__ __launch_bounds__(256) void k_gemm(float* __restrict__ io,
                                              const float* __restrict__ W,
                                              const float* __restrict__ bias,
                                              const float* __restrict__ deg,
                                              const int* __restrict__ num_nodes) {
    __shared__ float4 wl[128 * 32];           // W[k][c] as float4: wl[k*32 + c4]
    int t = threadIdx.x;
    const float4* Wv = (const float4*)W;
#pragma unroll
    for (int i = 0; i < 16; i++) wl[t + i * 256] = Wv[t + i * 256];
    __syncthreads();

    int row0 = blockIdx.x * 64;
    int cg = t & 15;                          // cols 8*cg .. 8*cg+7
    int rg = t >> 4;                          // rows 4*rg .. 4*rg+3
    const float* a0p = io + (size_t)(row0 + rg * 4 + 0) * CC;
    const float* a1p = io + (size_t)(row0 + rg * 4 + 1) * CC;
    const float* a2p = io + (size_t)(row0 + rg * 4 + 2) * CC;
    const float* a3p = io + (size_t)(row0 + rg * 4 + 3) * CC;

    float acc[4][8] = {};
#pragma unroll 2
    for (int kc = 0; kc < 128; kc += 4) {
        float4 a[4];
        a[0] = *(const float4*)(a0p + kc);
        a[1] = *(const float4*)(a1p + kc);
        a[2] = *(const float4*)(a2p + kc);
        a[3] = *(const float4*)(a3p + kc);
#pragma unroll
        for (int kk = 0; kk < 4; kk++) {
            float4 w0 = wl[(kc + kk) * 32 + cg * 2];
            float4 w1 = wl[(kc + kk) * 32 + cg * 2 + 1];
            float av[4];
            av[0] = (kk == 0) ? a[0].x : (kk == 1) ? a[0].y : (kk == 2) ? a[0].z : a[0].w;
            av[1] = (kk == 0) ? a[1].x : (kk == 1) ? a[1].y : (kk == 2) ? a[1].z : a[1].w;
            av[2] = (kk == 0) ? a[2].x : (kk == 1) ? a[2].y : (kk == 2) ? a[2].z : a[2].w;
            av[3] = (kk == 0) ? a[3].x : (kk == 1) ? a[3].y : (kk == 2) ? a[3].z : a[3].w;
#pragma unroll
            for (int i = 0; i < 4; i++) {
                acc[i][0] += av[i] * w0.x; acc[i][1] += av[i] * w0.y;
                acc[i][2] += av[i] * w0.z; acc[i][3] += av[i] * w0.w;
                acc[i][4] += av[i] * w1.x; acc[i][5] += av[i] * w1.y;
                acc[i][6] += av[i] * w1.z; acc[i][7] += av[i] * w1.w;
            }
        }
    }

    float4 b0 = *(const float4*)(bias + cg * 8);
    float4 b1 = *(const float4*)(bias + cg * 8 + 4);
    float bb[8] = { b0.x, b0.y, b0.z, b0.w, b1.x, b1.y, b1.z, b1.w };

#pragma unroll
    for (int i = 0; i < 4; i++) {
        int grow = row0 + rg * 4 + i;
        int b = grow / NN;
        int r = grow - b * NN;
        float d = deg[grow];
        float sc = 1.0f / fmaxf(d, 1.0f);
        bool alive = r < num_nodes[b];
        float o[8];
#pragma unroll
        for (int j = 0; j < 8; j++)
            o[j] = alive ? (acc[i][j] + d * bb[j]) * sc : 0.0f;
        float* dst = io + (size_t)grow * CC + cg * 8;
        *(float4*)(dst)     = make_float4(o[0], o[1], o[2], o[3]);
        *(float4*)(dst + 4) = make_float4(o[4], o[5], o[6], o[7]);
    }
}

extern "C" void kernel_launch(void* const* d_in, const int* in_sizes, int n_in,
                              void* d_out, int out_size, void* d_ws, size_t ws_size,
                              hipStream_t stream) {
    const float* x        = (const float*)d_in[0];
    const float* weight   = (const float*)d_in[1];
    const float* bias     = (const float*)d_in[2];
    const int*   edge_row = (const int*)d_in[3];
    const int*   edge_col = (const int*)d_in[4];
    const float* edge_val = (const float*)d_in[5];
    const int*   num_nodes= (const int*)d_in[6];
    float* out = (float*)d_out;

    int2*  binned  = (int2*)d_out;                      // phase-A scratch in d_out
    int2*  sorted  = (int2*)d_ws;                       // BG*NBKT*CAP int2
    float* deg     = (float*)(sorted + (size_t)BG * NBKT * CAP);
    int*   row_off = (int*)(deg + BN);
    int*   row_cnt = row_off + BN;
    int*   cursor  = row_cnt + BN;                      // BG*NBKT ints

    hipMemsetAsync(cursor, 0, BG * NBKT * sizeof(int), stream);
    k_bin<<<BG * BPG, 256, 0, stream>>>(edge_row, edge_col, edge_val, cursor, binned);
    k_sort<<<BG * NBKT, 256, 0, stream>>>(binned, cursor, sorted,
                                          row_off, row_cnt, deg);
    k_gather<<<8 * (NN / 4), 256, 0, stream>>>(x, row_off, row_cnt, sorted, out, 0);
    k_gather<<<8 * (NN / 4), 256, 0, stream>>>(x, row_off, row_cnt, sorted, out, 1);
    k_gemm<<<BN / 64, 256, 0, stream>>>(out, weight, bias, deg, num_nodes);
}

// Round 9
// 295.554 us; speedup vs baseline: 8.0786x; 1.0003x over previous
//
#include <hip/hip_runtime.h>

// Problem constants (match reference)
#define BG   8          // graphs
#define NN   10000      // nodes per graph
#define EE   320000     // edges per graph
#define CC   128        // channels (in == out)
#define BN   (BG*NN)    // 80000
#define BE   (BG*EE)    // 2560000

#define NBKT   157      // buckets per graph: ceil(10000/64), bkt = row >> 6
#define BROWS  64       // rows per bucket, row_local = row & 63
#define CAP    2560     // slots per bucket (mean 2048, sd ~45 -> 11 sigma)
#define CHUNK  4096     // edges per binning block
#define BPG    ((EE + CHUNK - 1) / CHUNK)   // 79 blocks per graph

// ---------------------------------------------------------------------------
// Buffers:
//   d_out (41 MB) doubles as the capacity-strided "binned" buffer
//   (BG*NBKT*CAP int2 = 25.7 MB), consumed by k_sort before k_gather
//   overwrites d_out with aggx.
// Workspace:
//   sorted   BG*NBKT*CAP int2 (25.7 MB)  row-sorted {col, val_bits}
//   deg      BN f32
//   row_off  BN int   (graph-local index into capacity-strided sorted)
//   row_cnt  BN int
//   cursor   BG*NBKT int   <- memset 0 each call
// total ~26.7 MB
// ---------------------------------------------------------------------------

__global__ __launch_bounds__(256) void k_bin(const int* __restrict__ edge_row,
                                             const int* __restrict__ edge_col,
                                             const float* __restrict__ edge_val,
                                             int* __restrict__ cursor,
                                             int2* __restrict__ binned) {
    int g = blockIdx.x / BPG;
    int cstart = (blockIdx.x % BPG) * CHUNK;
    int t = threadIdx.x;
    __shared__ int lh[NBKT];
    __shared__ int lbase[NBKT];
    for (int i = t; i < NBKT; i += 256) lh[i] = 0;
    __syncthreads();
    int rows[CHUNK / 256];
#pragma unroll
    for (int j = 0; j < CHUNK / 256; j++) {
        int e = cstart + j * 256 + t;
        if (e < EE) {
            int r = edge_row[(size_t)g * EE + e];
            rows[j] = r;
            atomicAdd(&lh[r >> 6], 1);
        } else rows[j] = -1;
    }
    __syncthreads();
    for (int i = t; i < NBKT; i += 256) {
        int c = lh[i];
        lbase[i] = c ? atomicAdd(&cursor[g * NBKT + i], c) : 0;
        lh[i] = 0;
    }
    __syncthreads();
#pragma unroll
    for (int j = 0; j < CHUNK / 256; j++) {
        if (rows[j] >= 0) {
            int e = cstart + j * 256 + t;
            int r = rows[j];
            int bkt = r >> 6;
            int pos = lbase[bkt] + atomicAdd(&lh[bkt], 1);
            binned[((size_t)g * NBKT + bkt) * CAP + pos] =
                make_int2(((r & 63) << 14) | edge_col[(size_t)g * EE + e],
                          __float_as_int(edge_val[(size_t)g * EE + e]));
        }
    }
}

// One block per (graph, bucket): LDS-resident counting sort by row_local.
// Coalesced read, LDS scatter, coalesced write. Emits row_off/cnt/deg.
__global__ __launch_bounds__(256) void k_sort(const int2* __restrict__ binned,
                                              const int* __restrict__ bcnt,
                                              int2* __restrict__ sorted,
                                              int* __restrict__ row_off,
                                              int* __restrict__ row_cnt,
                                              float* __restrict__ deg) {
    int g = blockIdx.x / NBKT;
    int bkt = blockIdx.x % NBKT;
    int t = threadIdx.x;
    __shared__ int2 ein[CAP];      // 20.5 KB
    __shared__ int2 eout[CAP];     // 20.5 KB
    __shared__ int cnts[BROWS], excl[BROWS], curs[BROWS];
    __shared__ float degl[BROWS];
    if (t < BROWS) { cnts[t] = 0; degl[t] = 0.f; }
    __syncthreads();
    int cnt = bcnt[g * NBKT + bkt];
    if (cnt > CAP) cnt = CAP;      // statistically impossible; memory safety
    const int2* src = binned + ((size_t)g * NBKT + bkt) * CAP;
    for (int i = t; i < cnt; i += 256) {
        int2 ed = src[i];
        ein[i] = ed;
        atomicAdd(&cnts[ed.x >> 14], 1);
        atomicAdd(&degl[ed.x >> 14], __int_as_float(ed.y));
    }
    __syncthreads();
    if (t < 64) {                  // wave 0: exclusive scan of 64 counts
        int own = cnts[t];
        int v = own;
#pragma unroll
        for (int d = 1; d < 64; d <<= 1) {
            int n = __shfl_up(v, d);
            if (t >= d) v += n;
        }
        excl[t] = v - own;
        curs[t] = v - own;
        int gr = bkt * BROWS + t;
        if (gr < NN) {
            int row = g * NN + gr;
            row_off[row] = bkt * CAP + (v - own);
            row_cnt[row] = own;
            deg[row] = degl[t];
        }
    }
    __syncthreads();
    for (int i = t; i < cnt; i += 256) {
        int2 ed = ein[i];
        int pos = atomicAdd(&curs[ed.x >> 14], 1);
        eout[pos] = make_int2(ed.x & 0x3FFF, ed.y);
    }
    __syncthreads();
    int2* dst = sorted + ((size_t)g * NBKT + bkt) * CAP;
    for (int i = t; i < cnt; i += 256) dst[i] = eout[i];
}

// One wave per row, one channel-half per pass (64 ch, lane owns 1 channel).
// Per-pass x working set = 2.56 MB/graph -> XCD-L2-resident (bid&7 = graph).
// Meta via nontemporal uniform loads + readfirstlane (SALU addressing);
// aggx written nontemporal to avoid evicting x from L2.
__global__ __launch_bounds__(256) void k_gather(const float* __restrict__ x,
                                                const int* __restrict__ row_off,
                                                const int* __restrict__ row_cnt,
                                                const int2* __restrict__ sorted,
                                                float* __restrict__ aggx,
                                                int pass) {
    int bid = blockIdx.x;
    int g = bid & 7;
    int chunk = bid >> 3;
    int wid = threadIdx.x >> 6, lane = threadIdx.x & 63;
    int r = chunk * 4 + wid;
    int bn = g * NN + r;
    int start = __builtin_amdgcn_readfirstlane(row_off[bn]);
    int cnt = __builtin_amdgcn_readfirstlane(row_cnt[bn]);
    const float* xb = x + (size_t)g * NN * CC + pass * 64 + lane;
    const long long* ep =
        (const long long*)(sorted + (size_t)g * NBKT * CAP + start);

    float a0 = 0.f, a1 = 0.f;
    int e = 0;
    for (; e + 8 <= cnt; e += 8) {
        int c[8]; float v[8];
#pragma unroll
        for (int j = 0; j < 8; j++) {
            long long m = __builtin_nontemporal_load(ep + e + j);
            c[j] = __builtin_amdgcn_readfirstlane((int)m);
            v[j] = __int_as_float(__builtin_amdgcn_readfirstlane((int)(m >> 32)));
        }
        float xv[8];
#pragma unroll
        for (int j = 0; j < 8; j++)
            xv[j] = xb[(size_t)c[j] << 7];
#pragma unroll
        for (int j = 0; j < 8; j++) {
            if (j & 1) a1 += v[j] * xv[j];
            else       a0 += v[j] * xv[j];
        }
    }
    for (; e < cnt; e++) {
        long long m = __builtin_nontemporal_load(ep + e);
        int c0 = __builtin_amdgcn_readfirstlane((int)m);
        float v0 = __int_as_float(__builtin_amdgcn_readfirstlane((int)(m >> 32)));
        a0 += v0 * xb[(size_t)c0 << 7];
    }
    __builtin_nontemporal_store(a0 + a1,
                                aggx + (size_t)bn * CC + pass * 64 + lane);
}

// out[row] = mask * (aggx[row] @ W + deg*bias) / max(deg,1)
// W in LDS (64 KB, 2 blocks/CU). Block tile 128 rows x 128 cols; thread owns
// 8 rows x cols {4cg..4cg+3, 64+4cg..64+4cg+3}. W-reads: 16 lanes x 16B at
// 16B stride = 256B contiguous -> 2-way bank aliasing only (free, m136).
__global__ __launch_bounds__(256) void k_gemm(float* __restrict__ io,
                                              const float* __restrict__ W,
                                              const float* __restrict__ bias,
                                              const float* __restrict__ deg,
                                              const int* __restrict__ num_nodes) {
    __shared__ float4 wl[128 * 32];           // wl[k*32 + c4], c4 = col/4
    int t = threadIdx.x;
    const float4* Wv = (const float4*)W;
#pragma unroll
    for (int i = 0; i < 16; i++) wl[t + i * 256] = Wv[t + i * 256];
    __syncthreads();

    int row0 = blockIdx.x * 128;
    int cg = t & 15;                          // col groups: 4cg and 64+4cg
    int rg = t >> 4;                          // rows 8*rg .. 8*rg+7
    const float* ap = io + (size_t)(row0 + rg * 8) * CC;

    float acc[8][8] = {};                     // [row][j]: j<4 -> 4cg+j, j>=4 -> 64+4cg+j-4
    for (int kc = 0; kc < 128; kc += 4) {
        float4 a[8];
#pragma unroll
        for (int i = 0; i < 8; i++)
            a[i] = *(const float4*)(ap + (size_t)i * CC + kc);
#pragma unroll
        for (int kk = 0; kk < 4; kk++) {
            float4 w0 = wl[(kc + kk) * 32 + cg];
            float4 w1 = wl[(kc + kk) * 32 + 16 + cg];
#pragma unroll
            for (int i = 0; i < 8; i++) {
                float av = (kk == 0) ? a[i].x : (kk == 1) ? a[i].y
                         : (kk == 2) ? a[i].z : a[i].w;
                acc[i][0] += av * w0.x; acc[i][1] += av * w0.y;
                acc[i][2] += av * w0.z; acc[i][3] += av * w0.w;
                acc[i][4] += av * w1.x; acc[i][5] += av * w1.y;
                acc[i][6] += av * w1.z; acc[i][7] += av * w1.w;
            }
        }
    }

    float4 b0 = *(const float4*)(bias + cg * 4);
    float4 b1 = *(const float4*)(bias + 64 + cg * 4);
    float bb[8] = { b0.x, b0.y, b0.z, b0.w, b1.x, b1.y, b1.z, b1.w };

#pragma unroll
    for (int i = 0; i < 8; i++) {
        int grow = row0 + rg * 8 + i;
        int b = grow / NN;
        int r = grow - b * NN;
        float d = deg[grow];
        float sc = 1.0f / fmaxf(d, 1.0f);
        bool alive = r < num_nodes[b];
        float o[8];
#pragma unroll
        for (int j = 0; j < 8; j++)
            o[j] = alive ? (acc[i][j] + d * bb[j]) * sc : 0.0f;
        float* dst = io + (size_t)grow * CC;
        *(float4*)(dst + cg * 4)      = make_float4(o[0], o[1], o[2], o[3]);
        *(float4*)(dst + 64 + cg * 4) = make_float4(o[4], o[5], o[6], o[7]);
    }
}

extern "C" void kernel_launch(void* const* d_in, const int* in_sizes, int n_in,
                              void* d_out, int out_size, void* d_ws, size_t ws_size,
                              hipStream_t stream) {
    const float* x        = (const float*)d_in[0];
    const float* weight   = (const float*)d_in[1];
    const float* bias     = (const float*)d_in[2];
    const int*   edge_row = (const int*)d_in[3];
    const int*   edge_col = (const int*)d_in[4];
    const float* edge_val = (const float*)d_in[5];
    const int*   num_nodes= (const int*)d_in[6];
    float* out = (float*)d_out;

    int2*  binned  = (int2*)d_out;                      // phase-A scratch in d_out
    int2*  sorted  = (int2*)d_ws;                       // BG*NBKT*CAP int2
    float* deg     = (float*)(sorted + (size_t)BG * NBKT * CAP);
    int*   row_off = (int*)(deg + BN);
    int*   row_cnt = row_off + BN;
    int*   cursor  = row_cnt + BN;                      // BG*NBKT ints

    hipMemsetAsync(cursor, 0, BG * NBKT * sizeof(int), stream);
    k_bin<<<BG * BPG, 256, 0, stream>>>(edge_row, edge_col, edge_val, cursor, binned);
    k_sort<<<BG * NBKT, 256, 0, stream>>>(binned, cursor, sorted,
                                          row_off, row_cnt, deg);
    k_gather<<<8 * (NN / 4), 256, 0, stream>>>(x, row_off, row_cnt, sorted, out, 0);
    k_gather<<<8 * (NN / 4), 256, 0, stream>>>(x, row_off, row_cnt, sorted, out, 1);
    k_gemm<<<BN / 128, 256, 0, stream>>>(out, weight, bias, deg, num_nodes);
}

// Round 10
// 295.295 us; speedup vs baseline: 8.0857x; 1.0009x over previous
//
#include <hip/hip_runtime.h>

// Problem constants (match reference)
#define BG   8          // graphs
#define NN   10000      // nodes per graph
#define EE   320000     // edges per graph
#define CC   128        // channels (in == out)
#define BN   (BG*NN)    // 80000
#define BE   (BG*EE)    // 2560000

#define NBKT   157      // buckets per graph: ceil(10000/64), bkt = row >> 6
#define BROWS  64       // rows per bucket, row_local = row & 63
#define CAP    2560     // slots per bucket (mean 2048, sd ~45 -> 11 sigma)
#define CHUNK  4096     // edges per binning block
#define BPG    ((EE + CHUNK - 1) / CHUNK)   // 79 blocks per graph

// ---------------------------------------------------------------------------
// Buffers:
//   d_out (41 MB) doubles as the capacity-strided "binned" buffer
//   (BG*NBKT*CAP int2 = 25.7 MB), consumed by k_sort before k_gather
//   overwrites d_out with aggx.
// Workspace:
//   sorted   BG*NBKT*CAP int2 (25.7 MB)  row-sorted {col, val_bits}
//   deg      BN f32
//   row_off  BN int   (graph-local index into capacity-strided sorted)
//   row_cnt  BN int
//   cursor   BG*NBKT int   <- memset 0 each call
// total ~26.7 MB
// ---------------------------------------------------------------------------

__global__ __launch_bounds__(256) void k_bin(const int* __restrict__ edge_row,
                                             const int* __restrict__ edge_col,
                                             const float* __restrict__ edge_val,
                                             int* __restrict__ cursor,
                                             int2* __restrict__ binned) {
    int g = blockIdx.x / BPG;
    int cstart = (blockIdx.x % BPG) * CHUNK;
    int t = threadIdx.x;
    __shared__ int lh[NBKT];
    __shared__ int lbase[NBKT];
    for (int i = t; i < NBKT; i += 256) lh[i] = 0;
    __syncthreads();
    int rows[CHUNK / 256];
    int pos[CHUNK / 256];
#pragma unroll
    for (int j = 0; j < CHUNK / 256; j++) {
        int e = cstart + j * 256 + t;
        if (e < EE) {
            int r = edge_row[(size_t)g * EE + e];
            rows[j] = r;
            pos[j] = atomicAdd(&lh[r >> 6], 1);
        } else rows[j] = -1;
    }
    __syncthreads();
    for (int i = t; i < NBKT; i += 256) {
        int c = lh[i];
        lbase[i] = c ? atomicAdd(&cursor[g * NBKT + i], c) : 0;
    }
    __syncthreads();
#pragma unroll
    for (int j = 0; j < CHUNK / 256; j++) {
        if (rows[j] >= 0) {
            int e = cstart + j * 256 + t;
            int r = rows[j];
            int bkt = r >> 6;
            binned[((size_t)g * NBKT + bkt) * CAP + lbase[bkt] + pos[j]] =
                make_int2(((r & 63) << 14) | edge_col[(size_t)g * EE + e],
                          __float_as_int(edge_val[(size_t)g * EE + e]));
        }
    }
}

// One block per (graph, bucket): LDS-resident counting sort by row_local.
// Coalesced read, LDS scatter, coalesced write. Emits row_off/cnt/deg.
__global__ __launch_bounds__(256) void k_sort(const int2* __restrict__ binned,
                                              const int* __restrict__ bcnt,
                                              int2* __restrict__ sorted,
                                              int* __restrict__ row_off,
                                              int* __restrict__ row_cnt,
                                              float* __restrict__ deg) {
    int g = blockIdx.x / NBKT;
    int bkt = blockIdx.x % NBKT;
    int t = threadIdx.x;
    __shared__ int2 ein[CAP];      // 20.5 KB
    __shared__ int2 eout[CAP];     // 20.5 KB
    __shared__ int cnts[BROWS], excl[BROWS], curs[BROWS];
    __shared__ float degl[BROWS];
    if (t < BROWS) { cnts[t] = 0; degl[t] = 0.f; }
    __syncthreads();
    int cnt = bcnt[g * NBKT + bkt];
    if (cnt > CAP) cnt = CAP;      // statistically impossible; memory safety
    const int2* src = binned + ((size_t)g * NBKT + bkt) * CAP;
    for (int i = t; i < cnt; i += 256) {
        int2 ed = src[i];
        ein[i] = ed;
        atomicAdd(&cnts[ed.x >> 14], 1);
        atomicAdd(&degl[ed.x >> 14], __int_as_float(ed.y));
    }
    __syncthreads();
    if (t < 64) {                  // wave 0: exclusive scan of 64 counts
        int own = cnts[t];
        int v = own;
#pragma unroll
        for (int d = 1; d < 64; d <<= 1) {
            int n = __shfl_up(v, d);
            if (t >= d) v += n;
        }
        excl[t] = v - own;
        curs[t] = v - own;
        int gr = bkt * BROWS + t;
        if (gr < NN) {
            int row = g * NN + gr;
            row_off[row] = bkt * CAP + (v - own);
            row_cnt[row] = own;
            deg[row] = degl[t];
        }
    }
    __syncthreads();
    for (int i = t; i < cnt; i += 256) {
        int2 ed = ein[i];
        int pos = atomicAdd(&curs[ed.x >> 14], 1);
        eout[pos] = make_int2(ed.x & 0x3FFF, ed.y);
    }
    __syncthreads();
    int2* dst = sorted + ((size_t)g * NBKT + bkt) * CAP;
    for (int i = t; i < cnt; i += 256) dst[i] = eout[i];
}

// One wave per row, one channel-half per pass (64 ch, lane owns 1 channel).
// Per-pass x working set = 2.56 MB/graph -> XCD-L2-resident (bid&7 = graph).
// Meta via nontemporal uniform loads + readfirstlane (SALU addressing);
// aggx written nontemporal to avoid evicting x from L2.
__global__ __launch_bounds__(256) void k_gather(const float* __restrict__ x,
                                                const int* __restrict__ row_off,
                                                const int* __restrict__ row_cnt,
                                                const int2* __restrict__ sorted,
                                                float* __restrict__ aggx,
                                                int pass) {
    int bid = blockIdx.x;
    int g = bid & 7;
    int chunk = bid >> 3;
    int wid = threadIdx.x >> 6, lane = threadIdx.x & 63;
    int r = chunk * 4 + wid;
    int bn = g * NN + r;
    int start = __builtin_amdgcn_readfirstlane(row_off[bn]);
    int cnt = __builtin_amdgcn_readfirstlane(row_cnt[bn]);
    const float* xb = x + (size_t)g * NN * CC + pass * 64 + lane;
    const long long* ep =
        (const long long*)(sorted + (size_t)g * NBKT * CAP + start);

    float a0 = 0.f, a1 = 0.f;
    int e = 0;
    for (; e + 8 <= cnt; e += 8) {
        int c[8]; float v[8];
#pragma unroll
        for (int j = 0; j < 8; j++) {
            long long m = __builtin_nontemporal_load(ep + e + j);
            c[j] = __builtin_amdgcn_readfirstlane((int)m);
            v[j] = __int_as_float(__builtin_amdgcn_readfirstlane((int)(m >> 32)));
        }
        float xv[8];
#pragma unroll
        for (int j = 0; j < 8; j++)
            xv[j] = xb[(size_t)c[j] << 7];
#pragma unroll
        for (int j = 0; j < 8; j++) {
            if (j & 1) a1 += v[j] * xv[j];
            else       a0 += v[j] * xv[j];
        }
    }
    for (; e < cnt; e++) {
        long long m = __builtin_nontemporal_load(ep + e);
        int c0 = __builtin_amdgcn_readfirstlane((int)m);
        float v0 = __int_as_float(__builtin_amdgcn_readfirstlane((int)(m >> 32)));
        a0 += v0 * xb[(size_t)c0 << 7];
    }
    __builtin_nontemporal_store(a0 + a1,
                                aggx + (size_t)bn * CC + pass * 64 + lane);
}

// out[row] = mask * (aggx[row] @ W + deg*bias) / max(deg,1)
// W staged in LDS in TWO 32 KB k-halves (rows 0-63, then 64-127) -> LDS cap
// lifts to 4+ blocks/CU; with VGPR=4 waves/SIMD all 625 blocks co-resident
// (no grid-quantization tail, which was the round-9 53 us cost).
// Thread owns 8 rows x cols {4cg..4cg+3, 64+4cg..4cg+3}; W-reads are 16 lanes
// x 16B contiguous -> 2-way bank aliasing only (free).
__global__ __launch_bounds__(256) void k_gemm(float* __restrict__ io,
                                              const float* __restrict__ W,
                                              const float* __restrict__ bias,
                                              const float* __restrict__ deg,
                                              const int* __restrict__ num_nodes) {
    __shared__ float4 wl[64 * 32];            // 32 KB: wl[kl*32 + c4]
    int t = threadIdx.x;
    const float4* Wv = (const float4*)W;

    int row0 = blockIdx.x * 128;
    int cg = t & 15;                          // col groups: 4cg and 64+4cg
    int rg = t >> 4;                          // rows 8*rg .. 8*rg+7
    const float* ap = io + (size_t)(row0 + rg * 8) * CC;

    float acc[8][8] = {};
    for (int h = 0; h < 2; h++) {
        __syncthreads();                      // previous half fully consumed
#pragma unroll
        for (int i = 0; i < 8; i++)
            wl[t + i * 256] = Wv[h * 2048 + t + i * 256];
        __syncthreads();
        int kbase = h * 64;
        for (int kc = 0; kc < 64; kc += 4) {
            float4 a[8];
#pragma unroll
            for (int i = 0; i < 8; i++)
                a[i] = *(const float4*)(ap + (size_t)i * CC + kbase + kc);
#pragma unroll
            for (int kk = 0; kk < 4; kk++) {
                float4 w0 = wl[(kc + kk) * 32 + cg];
                float4 w1 = wl[(kc + kk) * 32 + 16 + cg];
#pragma unroll
                for (int i = 0; i < 8; i++) {
                    float av = (kk == 0) ? a[i].x : (kk == 1) ? a[i].y
                             : (kk == 2) ? a[i].z : a[i].w;
                    acc[i][0] += av * w0.x; acc[i][1] += av * w0.y;
                    acc[i][2] += av * w0.z; acc[i][3] += av * w0.w;
                    acc[i][4] += av * w1.x; acc[i][5] += av * w1.y;
                    acc[i][6] += av * w1.z; acc[i][7] += av * w1.w;
                }
            }
        }
    }

    float4 b0 = *(const float4*)(bias + cg * 4);
    float4 b1 = *(const float4*)(bias + 64 + cg * 4);
    float bb[8] = { b0.x, b0.y, b0.z, b0.w, b1.x, b1.y, b1.z, b1.w };

#pragma unroll
    for (int i = 0; i < 8; i++) {
        int grow = row0 + rg * 8 + i;
        int b = grow / NN;
        int r = grow - b * NN;
        float d = deg[grow];
        float sc = 1.0f / fmaxf(d, 1.0f);
        bool alive = r < num_nodes[b];
        float o[8];
#pragma unroll
        for (int j = 0; j < 8; j++)
            o[j] = alive ? (acc[i][j] + d * bb[j]) * sc : 0.0f;
        float* dst = io + (size_t)grow * CC;
        *(float4*)(dst + cg * 4)      = make_float4(o[0], o[1], o[2], o[3]);
        *(float4*)(dst + 64 + cg * 4) = make_float4(o[4], o[5], o[6], o[7]);
    }
}

extern "C" void kernel_launch(void* const* d_in, const int* in_sizes, int n_in,
                              void* d_out, int out_size, void* d_ws, size_t ws_size,
                              hipStream_t stream) {
    const float* x        = (const float*)d_in[0];
    const float* weight   = (const float*)d_in[1];
    const float* bias     = (const float*)d_in[2];
    const int*   edge_row = (const int*)d_in[3];
    const int*   edge_col = (const int*)d_in[4];
    const float* edge_val = (const float*)d_in[5];
    const int*   num_nodes= (const int*)d_in[6];
    float* out = (float*)d_out;

    int2*  binned  = (int2*)d_out;                      // phase-A scratch in d_out
    int2*  sorted  = (int2*)d_ws;                       // BG*NBKT*CAP int2
    float* deg     = (float*)(sorted + (size_t)BG * NBKT * CAP);
    int*   row_off = (int*)(deg + BN);
    int*   row_cnt = row_off + BN;
    int*   cursor  = row_cnt + BN;                      // BG*NBKT ints

    hipMemsetAsync(cursor, 0, BG * NBKT * sizeof(int), stream);
    k_bin<<<BG * BPG, 256, 0, stream>>>(edge_row, edge_col, edge_val, cursor, binned);
    k_sort<<<BG * NBKT, 256, 0, stream>>>(binned, cursor, sorted,
                                          row_off, row_cnt, deg);
    k_gather<<<8 * (NN / 4), 256, 0, stream>>>(x, row_off, row_cnt, sorted, out, 0);
    k_gather<<<8 * (NN / 4), 256, 0, stream>>>(x, row_off, row_cnt, sorted, out, 1);
    k_gemm<<<BN / 128, 256, 0, stream>>>(out, weight, bias, deg, num_nodes);
}

// Round 11
// 293.079 us; speedup vs baseline: 8.1468x; 1.0076x over previous
//
#include <hip/hip_runtime.h>

// Problem constants (match reference)
#define BG   8          // graphs
#define NN   10000      // nodes per graph
#define EE   320000     // edges per graph
#define CC   128        // channels (in == out)
#define BN   (BG*NN)    // 80000
#define BE   (BG*EE)    // 2560000

#define NBKT   157      // buckets per graph: ceil(10000/64), bkt = row >> 6
#define BROWS  64       // rows per bucket, row_local = row & 63
#define CAP    2560     // slots per bucket (mean 2048, sd ~45 -> 11 sigma)
#define CHUNK  4096     // edges per binning block
#define BPG    ((EE + CHUNK - 1) / CHUNK)   // 79 blocks per graph

// ---------------------------------------------------------------------------
// Buffers:
//   d_out (41 MB) doubles as the capacity-strided "binned" buffer
//   (BG*NBKT*CAP int2 = 25.7 MB), consumed by k_sort before k_gather
//   overwrites d_out with aggx.
// Workspace:
//   sorted   BG*NBKT*CAP int2 (25.7 MB)  row-sorted {col, val_bits}
//   deg      BN f32
//   row_off  BN int   (graph-local index into capacity-strided sorted)
//   row_cnt  BN int
//   cursor   BG*NBKT int   <- memset 0 each call
// total ~26.7 MB
// ---------------------------------------------------------------------------

__global__ __launch_bounds__(256) void k_bin(const int* __restrict__ edge_row,
                                             const int* __restrict__ edge_col,
                                             const float* __restrict__ edge_val,
                                             int* __restrict__ cursor,
                                             int2* __restrict__ binned) {
    int g = blockIdx.x / BPG;
    int cstart = (blockIdx.x % BPG) * CHUNK;
    int t = threadIdx.x;
    __shared__ int lh[NBKT];
    __shared__ int lbase[NBKT];
    for (int i = t; i < NBKT; i += 256) lh[i] = 0;
    __syncthreads();
    int rows[CHUNK / 256];
    int pos[CHUNK / 256];
#pragma unroll
    for (int j = 0; j < CHUNK / 256; j++) {
        int e = cstart + j * 256 + t;
        if (e < EE) {
            int r = edge_row[(size_t)g * EE + e];
            rows[j] = r;
            pos[j] = atomicAdd(&lh[r >> 6], 1);
        } else rows[j] = -1;
    }
    __syncthreads();
    for (int i = t; i < NBKT; i += 256) {
        int c = lh[i];
        lbase[i] = c ? atomicAdd(&cursor[g * NBKT + i], c) : 0;
    }
    __syncthreads();
#pragma unroll
    for (int j = 0; j < CHUNK / 256; j++) {
        if (rows[j] >= 0) {
            int e = cstart + j * 256 + t;
            int r = rows[j];
            int bkt = r >> 6;
            binned[((size_t)g * NBKT + bkt) * CAP + lbase[bkt] + pos[j]] =
                make_int2(((r & 63) << 14) | edge_col[(size_t)g * EE + e],
                          __float_as_int(edge_val[(size_t)g * EE + e]));
        }
    }
}

// One block per (graph, bucket): LDS-resident counting sort by row_local.
// Coalesced read, LDS scatter, coalesced write. Emits row_off/cnt/deg.
__global__ __launch_bounds__(256) void k_sort(const int2* __restrict__ binned,
                                              const int* __restrict__ bcnt,
                                              int2* __restrict__ sorted,
                                              int* __restrict__ row_off,
                                              int* __restrict__ row_cnt,
                                              float* __restrict__ deg) {
    int g = blockIdx.x / NBKT;
    int bkt = blockIdx.x % NBKT;
    int t = threadIdx.x;
    __shared__ int2 ein[CAP];      // 20.5 KB
    __shared__ int2 eout[CAP];     // 20.5 KB
    __shared__ int cnts[BROWS], excl[BROWS], curs[BROWS];
    __shared__ float degl[BROWS];
    if (t < BROWS) { cnts[t] = 0; degl[t] = 0.f; }
    __syncthreads();
    int cnt = bcnt[g * NBKT + bkt];
    if (cnt > CAP) cnt = CAP;      // statistically impossible; memory safety
    const int2* src = binned + ((size_t)g * NBKT + bkt) * CAP;
    for (int i = t; i < cnt; i += 256) {
        int2 ed = src[i];
        ein[i] = ed;
        atomicAdd(&cnts[ed.x >> 14], 1);
        atomicAdd(&degl[ed.x >> 14], __int_as_float(ed.y));
    }
    __syncthreads();
    if (t < 64) {                  // wave 0: exclusive scan of 64 counts
        int own = cnts[t];
        int v = own;
#pragma unroll
        for (int d = 1; d < 64; d <<= 1) {
            int n = __shfl_up(v, d);
            if (t >= d) v += n;
        }
        excl[t] = v - own;
        curs[t] = v - own;
        int gr = bkt * BROWS + t;
        if (gr < NN) {
            int row = g * NN + gr;
            row_off[row] = bkt * CAP + (v - own);
            row_cnt[row] = own;
            deg[row] = degl[t];
        }
    }
    __syncthreads();
    for (int i = t; i < cnt; i += 256) {
        int2 ed = ein[i];
        int pos = atomicAdd(&curs[ed.x >> 14], 1);
        eout[pos] = make_int2(ed.x & 0x3FFF, ed.y);
    }
    __syncthreads();
    int2* dst = sorted + ((size_t)g * NBKT + bkt) * CAP;
    for (int i = t; i < cnt; i += 256) dst[i] = eout[i];
}

// One wave per row, one channel-half per pass (64 ch, lane owns 1 channel).
// Per-pass x working set = 2.56 MB/graph -> XCD-L2-resident (bid&7 = graph).
// Meta via nontemporal uniform loads + readfirstlane (SALU addressing).
// aggx stored NORMALLY (not nontemporal) so it stays L2-hot for k_gemm.
__global__ __launch_bounds__(256) void k_gather(const float* __restrict__ x,
                                                const int* __restrict__ row_off,
                                                const int* __restrict__ row_cnt,
                                                const int2* __restrict__ sorted,
                                                float* __restrict__ aggx,
                                                int pass) {
    int bid = blockIdx.x;
    int g = bid & 7;
    int chunk = bid >> 3;
    int wid = threadIdx.x >> 6, lane = threadIdx.x & 63;
    int r = chunk * 4 + wid;
    int bn = g * NN + r;
    int start = __builtin_amdgcn_readfirstlane(row_off[bn]);
    int cnt = __builtin_amdgcn_readfirstlane(row_cnt[bn]);
    const float* xb = x + (size_t)g * NN * CC + pass * 64 + lane;
    const long long* ep =
        (const long long*)(sorted + (size_t)g * NBKT * CAP + start);

    float a0 = 0.f, a1 = 0.f;
    int e = 0;
    for (; e + 8 <= cnt; e += 8) {
        int c[8]; float v[8];
#pragma unroll
        for (int j = 0; j < 8; j++) {
            long long m = __builtin_nontemporal_load(ep + e + j);
            c[j] = __builtin_amdgcn_readfirstlane((int)m);
            v[j] = __int_as_float(__builtin_amdgcn_readfirstlane((int)(m >> 32)));
        }
        float xv[8];
#pragma unroll
        for (int j = 0; j < 8; j++)
            xv[j] = xb[(size_t)c[j] << 7];
#pragma unroll
        for (int j = 0; j < 8; j++) {
            if (j & 1) a1 += v[j] * xv[j];
            else       a0 += v[j] * xv[j];
        }
    }
    for (; e < cnt; e++) {
        long long m = __builtin_nontemporal_load(ep + e);
        int c0 = __builtin_amdgcn_readfirstlane((int)m);
        float v0 = __int_as_float(__builtin_amdgcn_readfirstlane((int)(m >> 32)));
        a0 += v0 * xb[(size_t)c0 << 7];
    }
    aggx[(size_t)bn * CC + pass * 64 + lane] = a0 + a1;
}

// out[row] = mask * (aggx[row] @ W + deg*bias) / max(deg,1)
// 64-row tile (grid 1250) + two 32 KB W k-halves -> 5 blocks/CU LDS cap,
// ~4.9 blocks/CU resident (~20 waves/CU of latency hiding; round-10's 625
// blocks = 2.4/CU was the stall source). Thread: 4 rows x cols
// {4cg..4cg+3, 64+4cg..+3}; W-reads 16 lanes x 16B contiguous (conflict-free).
__global__ __launch_bounds__(256) void k_gemm(float* __restrict__ io,
                                              const float* __restrict__ W,
                                              const float* __restrict__ bias,
                                              const float* __restrict__ deg,
                                              const int* __restrict__ num_nodes) {
    __shared__ float4 wl[64 * 32];            // 32 KB: wl[kl*32 + c4]
    int t = threadIdx.x;
    const float4* Wv = (const float4*)W;

    int row0 = blockIdx.x * 64;
    int cg = t & 15;                          // col groups: 4cg and 64+4cg
    int rg = t >> 4;                          // rows 4*rg .. 4*rg+3
    const float* ap = io + (size_t)(row0 + rg * 4) * CC;

    float acc[4][8] = {};
    for (int h = 0; h < 2; h++) {
        __syncthreads();                      // previous half fully consumed
#pragma unroll
        for (int i = 0; i < 8; i++)
            wl[t + i * 256] = Wv[h * 2048 + t + i * 256];
        __syncthreads();
        int kbase = h * 64;
        for (int kc = 0; kc < 64; kc += 4) {
            float4 a[4];
#pragma unroll
            for (int i = 0; i < 4; i++)
                a[i] = *(const float4*)(ap + (size_t)i * CC + kbase + kc);
#pragma unroll
            for (int kk = 0; kk < 4; kk++) {
                float4 w0 = wl[(kc + kk) * 32 + cg];
                float4 w1 = wl[(kc + kk) * 32 + 16 + cg];
#pragma unroll
                for (int i = 0; i < 4; i++) {
                    float av = (kk == 0) ? a[i].x : (kk == 1) ? a[i].y
                             : (kk == 2) ? a[i].z : a[i].w;
                    acc[i][0] += av * w0.x; acc[i][1] += av * w0.y;
                    acc[i][2] += av * w0.z; acc[i][3] += av * w0.w;
                    acc[i][4] += av * w1.x; acc[i][5] += av * w1.y;
                    acc[i][6] += av * w1.z; acc[i][7] += av * w1.w;
                }
            }
        }
    }

    float4 b0 = *(const float4*)(bias + cg * 4);
    float4 b1 = *(const float4*)(bias + 64 + cg * 4);
    float bb[8] = { b0.x, b0.y, b0.z, b0.w, b1.x, b1.y, b1.z, b1.w };

#pragma unroll
    for (int i = 0; i < 4; i++) {
        int grow = row0 + rg * 4 + i;
        int b = grow / NN;
        int r = grow - b * NN;
        float d = deg[grow];
        float sc = 1.0f / fmaxf(d, 1.0f);
        bool alive = r < num_nodes[b];
        float o[8];
#pragma unroll
        for (int j = 0; j < 8; j++)
            o[j] = alive ? (acc[i][j] + d * bb[j]) * sc : 0.0f;
        float* dst = io + (size_t)grow * CC;
        *(float4*)(dst + cg * 4)      = make_float4(o[0], o[1], o[2], o[3]);
        *(float4*)(dst + 64 + cg * 4) = make_float4(o[4], o[5], o[6], o[7]);
    }
}

extern "C" void kernel_launch(void* const* d_in, const int* in_sizes, int n_in,
                              void* d_out, int out_size, void* d_ws, size_t ws_size,
                              hipStream_t stream) {
    const float* x        = (const float*)d_in[0];
    const float* weight   = (const float*)d_in[1];
    const float* bias     = (const float*)d_in[2];
    const int*   edge_row = (const int*)d_in[3];
    const int*   edge_col = (const int*)d_in[4];
    const float* edge_val = (const float*)d_in[5];
    const int*   num_nodes= (const int*)d_in[6];
    float* out = (float*)d_out;

    int2*  binned  = (int2*)d_out;                      // phase-A scratch in d_out
    int2*  sorted  = (int2*)d_ws;                       // BG*NBKT*CAP int2
    float* deg     = (float*)(sorted + (size_t)BG * NBKT * CAP);
    int*   row_off = (int*)(deg + BN);
    int*   row_cnt = row_off + BN;
    int*   cursor  = row_cnt + BN;                      // BG*NBKT ints

    hipMemsetAsync(cursor, 0, BG * NBKT * sizeof(int), stream);
    k_bin<<<BG * BPG, 256, 0, stream>>>(edge_row, edge_col, edge_val, cursor, binned);
    k_sort<<<BG * NBKT, 256, 0, stream>>>(binned, cursor, sorted,
                                          row_off, row_cnt, deg);
    k_gather<<<8 * (NN / 4), 256, 0, stream>>>(x, row_off, row_cnt, sorted, out, 0);
    k_gather<<<8 * (NN / 4), 256, 0, stream>>>(x, row_off, row_cnt, sorted, out, 1);
    k_gemm<<<BN / 64, 256, 0, stream>>>(out, weight, bias, deg, num_nodes);
}

// Round 12
// 285.826 us; speedup vs baseline: 8.3535x; 1.0254x over previous
//
#include <hip/hip_runtime.h>

// Problem constants (match reference)
#define BG   8          // graphs
#define NN   10000      // nodes per graph
#define EE   320000     // edges per graph
#define CC   128        // channels (in == out)
#define BN   (BG*NN)    // 80000
#define BE   (BG*EE)    // 2560000

#define NBKT   157      // buckets per graph: ceil(10000/64), bkt = row >> 6
#define BROWS  64       // rows per bucket, row_local = row & 63
#define CAP    2560     // slots per bucket (mean 2048, sd ~45 -> 11 sigma)
#define CHUNK  4096     // edges per binning block
#define BPG    ((EE + CHUNK - 1) / CHUNK)   // 79 blocks per graph

#define RFL(x) __builtin_amdgcn_readfirstlane(x)

// ---------------------------------------------------------------------------
// Buffers:
//   d_out (41 MB) doubles as the capacity-strided "binned" buffer
//   (BG*NBKT*CAP int2 = 25.7 MB), consumed by k_sort before k_gather
//   overwrites d_out with aggx.
// Workspace:
//   sorted   BG*NBKT*CAP int2 (25.7 MB)  row-sorted {col, val_bits}
//   deg      BN f32
//   row_off  BN int   (graph-local index into capacity-strided sorted)
//   row_cnt  BN int
//   cursor   BG*NBKT int   <- memset 0 each call
// ---------------------------------------------------------------------------

__global__ __launch_bounds__(256) void k_bin(const int* __restrict__ edge_row,
                                             const int* __restrict__ edge_col,
                                             const float* __restrict__ edge_val,
                                             int* __restrict__ cursor,
                                             int2* __restrict__ binned) {
    int g = blockIdx.x / BPG;
    int cstart = (blockIdx.x % BPG) * CHUNK;
    int t = threadIdx.x;
    __shared__ int lh[NBKT];
    __shared__ int lbase[NBKT];
    for (int i = t; i < NBKT; i += 256) lh[i] = 0;
    __syncthreads();
    int rows[CHUNK / 256];
    int pos[CHUNK / 256];
#pragma unroll
    for (int j = 0; j < CHUNK / 256; j++) {
        int e = cstart + j * 256 + t;
        if (e < EE) {
            int r = edge_row[(size_t)g * EE + e];
            rows[j] = r;
            pos[j] = atomicAdd(&lh[r >> 6], 1);
        } else rows[j] = -1;
    }
    __syncthreads();
    for (int i = t; i < NBKT; i += 256) {
        int c = lh[i];
        lbase[i] = c ? atomicAdd(&cursor[g * NBKT + i], c) : 0;
    }
    __syncthreads();
#pragma unroll
    for (int j = 0; j < CHUNK / 256; j++) {
        if (rows[j] >= 0) {
            int e = cstart + j * 256 + t;
            int r = rows[j];
            int bkt = r >> 6;
            binned[((size_t)g * NBKT + bkt) * CAP + lbase[bkt] + pos[j]] =
                make_int2(((r & 63) << 14) | edge_col[(size_t)g * EE + e],
                          __float_as_int(edge_val[(size_t)g * EE + e]));
        }
    }
}

// One block per (graph, bucket): LDS-resident counting sort by row_local.
__global__ __launch_bounds__(256) void k_sort(const int2* __restrict__ binned,
                                              const int* __restrict__ bcnt,
                                              int2* __restrict__ sorted,
                                              int* __restrict__ row_off,
                                              int* __restrict__ row_cnt,
                                              float* __restrict__ deg) {
    int g = blockIdx.x / NBKT;
    int bkt = blockIdx.x % NBKT;
    int t = threadIdx.x;
    __shared__ int2 ein[CAP];      // 20.5 KB
    __shared__ int2 eout[CAP];     // 20.5 KB
    __shared__ int cnts[BROWS], excl[BROWS], curs[BROWS];
    __shared__ float degl[BROWS];
    if (t < BROWS) { cnts[t] = 0; degl[t] = 0.f; }
    __syncthreads();
    int cnt = bcnt[g * NBKT + bkt];
    if (cnt > CAP) cnt = CAP;      // statistically impossible; memory safety
    const int2* src = binned + ((size_t)g * NBKT + bkt) * CAP;
    for (int i = t; i < cnt; i += 256) {
        int2 ed = src[i];
        ein[i] = ed;
        atomicAdd(&cnts[ed.x >> 14], 1);
        atomicAdd(&degl[ed.x >> 14], __int_as_float(ed.y));
    }
    __syncthreads();
    if (t < 64) {                  // wave 0: exclusive scan of 64 counts
        int own = cnts[t];
        int v = own;
#pragma unroll
        for (int d = 1; d < 64; d <<= 1) {
            int n = __shfl_up(v, d);
            if (t >= d) v += n;
        }
        excl[t] = v - own;
        curs[t] = v - own;
        int gr = bkt * BROWS + t;
        if (gr < NN) {
            int row = g * NN + gr;
            row_off[row] = bkt * CAP + (v - own);
            row_cnt[row] = own;
            deg[row] = degl[t];
        }
    }
    __syncthreads();
    for (int i = t; i < cnt; i += 256) {
        int2 ed = ein[i];
        int pos = atomicAdd(&curs[ed.x >> 14], 1);
        eout[pos] = make_int2(ed.x & 0x3FFF, ed.y);
    }
    __syncthreads();
    int2* dst = sorted + ((size_t)g * NBKT + bkt) * CAP;
    for (int i = t; i < cnt; i += 256) dst[i] = eout[i];
}

// One wave per row, channel-half per pass. 2-deep software pipeline:
// slot g extracts meta(g) (loaded 2 slots ago), issues gathers(g) and
// meta-load(g+2), FMAs group g-1. E/O static double-buffering (no runtime
// indexing -> stays in registers). Meta prefetch may read <=16 edges past
// row end: stays inside the bucket's CAP region (safe), never used as gather.
__global__ __launch_bounds__(256) void k_gather(const float* __restrict__ x,
                                                const int* __restrict__ row_off,
                                                const int* __restrict__ row_cnt,
                                                const int2* __restrict__ sorted,
                                                float* __restrict__ aggx,
                                                int pass) {
    int bid = blockIdx.x;
    int g = bid & 7;
    int chunk = bid >> 3;
    int wid = threadIdx.x >> 6, lane = threadIdx.x & 63;
    int r = chunk * 4 + wid;
    int bn = g * NN + r;
    int start = RFL(row_off[bn]);
    int cnt = RFL(row_cnt[bn]);
    const float* xb = x + (size_t)g * NN * CC + pass * 64 + lane;
    const long long* ep =
        (const long long*)(sorted + (size_t)g * NBKT * CAP + start);

    float acc = 0.f;
    int G = cnt >> 3;
    int e = 0;
    if (G >= 2) {
        long long rawE[8], rawO[8];
        float xvE[8], xvO[8];
        float vE[8], vO[8];
#pragma unroll
        for (int j = 0; j < 8; j++) rawE[j] = ep[j];
#pragma unroll
        for (int j = 0; j < 8; j++) rawO[j] = ep[8 + j];
        // slot 0 (even): extract g0, gather g0, refill E with g2 meta
        int cE[8], cO[8];
#pragma unroll
        for (int j = 0; j < 8; j++) {
            cE[j] = RFL((int)rawE[j]);
            vE[j] = __int_as_float(RFL((int)(rawE[j] >> 32)));
        }
#pragma unroll
        for (int j = 0; j < 8; j++) xvE[j] = xb[(size_t)cE[j] << 7];
#pragma unroll
        for (int j = 0; j < 8; j++) rawE[j] = ep[16 + j];

        int gi = 1;
        for (; gi + 1 < G; gi += 2) {
            // odd slot gi: extract O, gather O, refill O meta, FMA E(gi-1)
#pragma unroll
            for (int j = 0; j < 8; j++) {
                cO[j] = RFL((int)rawO[j]);
                vO[j] = __int_as_float(RFL((int)(rawO[j] >> 32)));
            }
#pragma unroll
            for (int j = 0; j < 8; j++) xvO[j] = xb[(size_t)cO[j] << 7];
#pragma unroll
            for (int j = 0; j < 8; j++) rawO[j] = ep[(gi + 2) * 8 + j];
#pragma unroll
            for (int j = 0; j < 8; j++) acc += vE[j] * xvE[j];
            // even slot gi+1: extract E, gather E, refill E meta, FMA O(gi)
#pragma unroll
            for (int j = 0; j < 8; j++) {
                cE[j] = RFL((int)rawE[j]);
                vE[j] = __int_as_float(RFL((int)(rawE[j] >> 32)));
            }
#pragma unroll
            for (int j = 0; j < 8; j++) xvE[j] = xb[(size_t)cE[j] << 7];
#pragma unroll
            for (int j = 0; j < 8; j++) rawE[j] = ep[(gi + 3) * 8 + j];
#pragma unroll
            for (int j = 0; j < 8; j++) acc += vO[j] * xvO[j];
        }
        if (gi < G) {
            // one trailing odd slot: extract+gather O, FMA E then O
#pragma unroll
            for (int j = 0; j < 8; j++) {
                cO[j] = RFL((int)rawO[j]);
                vO[j] = __int_as_float(RFL((int)(rawO[j] >> 32)));
            }
#pragma unroll
            for (int j = 0; j < 8; j++) xvO[j] = xb[(size_t)cO[j] << 7];
#pragma unroll
            for (int j = 0; j < 8; j++) acc += vE[j] * xvE[j];
#pragma unroll
            for (int j = 0; j < 8; j++) acc += vO[j] * xvO[j];
        } else {
            // pipeline drained on an even boundary: final E FMA
#pragma unroll
            for (int j = 0; j < 8; j++) acc += vE[j] * xvE[j];
        }
        e = G * 8;
    }
    for (; e < cnt; e++) {
        long long m = ep[e];
        int c0 = RFL((int)m);
        float v0 = __int_as_float(RFL((int)(m >> 32)));
        acc += v0 * xb[(size_t)c0 << 7];
    }
    aggx[(size_t)bn * CC + pass * 64 + lane] = acc;
}

// out[row] = mask * (aggx[row] @ W + deg*bias) / max(deg,1)
// 64-row tile (grid 1250) + two 32 KB W k-halves (round-11 config, verified:
// dropped out of top-5). W-reads 16 lanes x 16B contiguous (conflict-free).
__global__ __launch_bounds__(256) void k_gemm(float* __restrict__ io,
                                              const float* __restrict__ W,
                                              const float* __restrict__ bias,
                                              const float* __restrict__ deg,
                                              const int* __restrict__ num_nodes) {
    __shared__ float4 wl[64 * 32];            // 32 KB: wl[kl*32 + c4]
    int t = threadIdx.x;
    const float4* Wv = (const float4*)W;

    int row0 = blockIdx.x * 64;
    int cg = t & 15;                          // col groups: 4cg and 64+4cg
    int rg = t >> 4;                          // rows 4*rg .. 4*rg+3
    const float* ap = io + (size_t)(row0 + rg * 4) * CC;

    float acc[4][8] = {};
    for (int h = 0; h < 2; h++) {
        __syncthreads();                      // previous half fully consumed
#pragma unroll
        for (int i = 0; i < 8; i++)
            wl[t + i * 256] = Wv[h * 2048 + t + i * 256];
        __syncthreads();
        int kbase = h * 64;
        for (int kc = 0; kc < 64; kc += 4) {
            float4 a[4];
#pragma unroll
            for (int i = 0; i < 4; i++)
                a[i] = *(const float4*)(ap + (size_t)i * CC + kbase + kc);
#pragma unroll
            for (int kk = 0; kk < 4; kk++) {
                float4 w0 = wl[(kc + kk) * 32 + cg];
                float4 w1 = wl[(kc + kk) * 32 + 16 + cg];
#pragma unroll
                for (int i = 0; i < 4; i++) {
                    float av = (kk == 0) ? a[i].x : (kk == 1) ? a[i].y
                             : (kk == 2) ? a[i].z : a[i].w;
                    acc[i][0] += av * w0.x; acc[i][1] += av * w0.y;
                    acc[i][2] += av * w0.z; acc[i][3] += av * w0.w;
                    acc[i][4] += av * w1.x; acc[i][5] += av * w1.y;
                    acc[i][6] += av * w1.z; acc[i][7] += av * w1.w;
                }
            }
        }
    }

    float4 b0 = *(const float4*)(bias + cg * 4);
    float4 b1 = *(const float4*)(bias + 64 + cg * 4);
    float bb[8] = { b0.x, b0.y, b0.z, b0.w, b1.x, b1.y, b1.z, b1.w };

#pragma unroll
    for (int i = 0; i < 4; i++) {
        int grow = row0 + rg * 4 + i;
        int b = grow / NN;
        int r = grow - b * NN;
        float d = deg[grow];
        float sc = 1.0f / fmaxf(d, 1.0f);
        bool alive = r < num_nodes[b];
        float o[8];
#pragma unroll
        for (int j = 0; j < 8; j++)
            o[j] = alive ? (acc[i][j] + d * bb[j]) * sc : 0.0f;
        float* dst = io + (size_t)grow * CC;
        *(float4*)(dst + cg * 4)      = make_float4(o[0], o[1], o[2], o[3]);
        *(float4*)(dst + 64 + cg * 4) = make_float4(o[4], o[5], o[6], o[7]);
    }
}

extern "C" void kernel_launch(void* const* d_in, const int* in_sizes, int n_in,
                              void* d_out, int out_size, void* d_ws, size_t ws_size,
                              hipStream_t stream) {
    const float* x        = (const float*)d_in[0];
    const float* weight   = (const float*)d_in[1];
    const float* bias     = (const float*)d_in[2];
    const int*   edge_row = (const int*)d_in[3];
    const int*   edge_col = (const int*)d_in[4];
    const float* edge_val = (const float*)d_in[5];
    const int*   num_nodes= (const int*)d_in[6];
    float* out = (float*)d_out;

    int2*  binned  = (int2*)d_out;                      // phase-A scratch in d_out
    int2*  sorted  = (int2*)d_ws;                       // BG*NBKT*CAP int2
    float* deg     = (float*)(sorted + (size_t)BG * NBKT * CAP);
    int*   row_off = (int*)(deg + BN);
    int*   row_cnt = row_off + BN;
    int*   cursor  = row_cnt + BN;                      // BG*NBKT ints

    hipMemsetAsync(cursor, 0, BG * NBKT * sizeof(int), stream);
    k_bin<<<BG * BPG, 256, 0, stream>>>(edge_row, edge_col, edge_val, cursor, binned);
    k_sort<<<BG * NBKT, 256, 0, stream>>>(binned, cursor, sorted,
                                          row_off, row_cnt, deg);
    k_gather<<<8 * (NN / 4), 256, 0, stream>>>(x, row_off, row_cnt, sorted, out, 0);
    k_gather<<<8 * (NN / 4), 256, 0, stream>>>(x, row_off, row_cnt, sorted, out, 1);
    k_gemm<<<BN / 64, 256, 0, stream>>>(out, weight, bias, deg, num_nodes);
}

// Round 14
// 282.030 us; speedup vs baseline: 8.4660x; 1.0135x over previous
//
#include <hip/hip_runtime.h>

// Problem constants (match reference)
#define BG   8          // graphs
#define NN   10000      // nodes per graph
#define EE   320000     // edges per graph
#define CC   128        // channels (in == out)
#define BN   (BG*NN)    // 80000
#define BE   (BG*EE)    // 2560000

#define NBKT   157      // buckets per graph: ceil(10000/64), bkt = row >> 6
#define BROWS  64       // rows per bucket, row_local = row & 63
#define CAP    2560     // slots per bucket (mean 2048, sd ~45 -> 11 sigma)
#define CHUNK  2048     // edges per binning block (1256 blocks -> ~5/CU)
#define BPG    ((EE + CHUNK - 1) / CHUNK)   // 157 blocks per graph

#define RFL(x) __builtin_amdgcn_readfirstlane(x)

// ---------------------------------------------------------------------------
// Buffers:
//   d_out (41 MB) doubles as the capacity-strided "binned" buffer
//   (BG*NBKT*CAP int2 = 25.7 MB), consumed by k_sort before k_gather
//   overwrites d_out with aggx.
// Workspace:
//   sorted   BG*NBKT*CAP int2 (25.7 MB)  row-sorted {col, val_bits}
//   deg      BN f32
//   row_off  BN int   (graph-local index into capacity-strided sorted)
//   row_cnt  BN int
//   cursor   BG*NBKT int   <- memset 0 each call
// ---------------------------------------------------------------------------

__global__ __launch_bounds__(256) void k_bin(const int* __restrict__ edge_row,
                                             const int* __restrict__ edge_col,
                                             const float* __restrict__ edge_val,
                                             int* __restrict__ cursor,
                                             int2* __restrict__ binned) {
    int g = blockIdx.x / BPG;
    int cstart = (blockIdx.x % BPG) * CHUNK;
    int t = threadIdx.x;
    __shared__ int lh[NBKT];
    __shared__ int lbase[NBKT];
    for (int i = t; i < NBKT; i += 256) lh[i] = 0;
    __syncthreads();
    int rows[CHUNK / 256];
    int pos[CHUNK / 256];
#pragma unroll
    for (int j = 0; j < CHUNK / 256; j++) {
        int e = cstart + j * 256 + t;
        if (e < EE) {
            int r = edge_row[(size_t)g * EE + e];
            rows[j] = r;
            pos[j] = atomicAdd(&lh[r >> 6], 1);
        } else rows[j] = -1;
    }
    __syncthreads();
    for (int i = t; i < NBKT; i += 256) {
        int c = lh[i];
        lbase[i] = c ? atomicAdd(&cursor[g * NBKT + i], c) : 0;
    }
    __syncthreads();
#pragma unroll
    for (int j = 0; j < CHUNK / 256; j++) {
        if (rows[j] >= 0) {
            int e = cstart + j * 256 + t;
            int r = rows[j];
            int bkt = r >> 6;
            binned[((size_t)g * NBKT + bkt) * CAP + lbase[bkt] + pos[j]] =
                make_int2(((r & 63) << 14) | edge_col[(size_t)g * EE + e],
                          __float_as_int(edge_val[(size_t)g * EE + e]));
        }
    }
}

// One block per (graph, bucket): LDS-resident counting sort by row_local.
__global__ __launch_bounds__(256) void k_sort(const int2* __restrict__ binned,
                                              const int* __restrict__ bcnt,
                                              int2* __restrict__ sorted,
                                              int* __restrict__ row_off,
                                              int* __restrict__ row_cnt,
                                              float* __restrict__ deg) {
    int g = blockIdx.x / NBKT;
    int bkt = blockIdx.x % NBKT;
    int t = threadIdx.x;
    __shared__ int2 ein[CAP];      // 20.5 KB
    __shared__ int2 eout[CAP];     // 20.5 KB
    __shared__ int cnts[BROWS], excl[BROWS], curs[BROWS];
    __shared__ float degl[BROWS];
    if (t < BROWS) { cnts[t] = 0; degl[t] = 0.f; }
    __syncthreads();
    int cnt = bcnt[g * NBKT + bkt];
    if (cnt > CAP) cnt = CAP;      // statistically impossible; memory safety
    const int2* src = binned + ((size_t)g * NBKT + bkt) * CAP;
    for (int i = t; i < cnt; i += 256) {
        int2 ed = src[i];
        ein[i] = ed;
        atomicAdd(&cnts[ed.x >> 14], 1);
        atomicAdd(&degl[ed.x >> 14], __int_as_float(ed.y));
    }
    __syncthreads();
    if (t < 64) {                  // wave 0: exclusive scan of 64 counts
        int own = cnts[t];
        int v = own;
#pragma unroll
        for (int d = 1; d < 64; d <<= 1) {
            int n = __shfl_up(v, d);
            if (t >= d) v += n;
        }
        excl[t] = v - own;
        curs[t] = v - own;
        int gr = bkt * BROWS + t;
        if (gr < NN) {
            int row = g * NN + gr;
            row_off[row] = bkt * CAP + (v - own);
            row_cnt[row] = own;
            deg[row] = degl[t];
        }
    }
    __syncthreads();
    for (int i = t; i < cnt; i += 256) {
        int2 ed = ein[i];
        int pos = atomicAdd(&curs[ed.x >> 14], 1);
        eout[pos] = make_int2(ed.x & 0x3FFF, ed.y);
    }
    __syncthreads();
    int2* dst = sorted + ((size_t)g * NBKT + bkt) * CAP;
    for (int i = t; i < cnt; i += 256) dst[i] = eout[i];
}

// One wave per row, channel-half per pass; BOTH passes in one launch
// (pass = upper grid half, so pass 0 mostly drains before pass 1 starts and
// the per-XCD L2 working set stays 2.56 MB). 2-deep E/O software pipeline.
__global__ __launch_bounds__(256) void k_gather(const float* __restrict__ x,
                                                const int* __restrict__ row_off,
                                                const int* __restrict__ row_cnt,
                                                const int2* __restrict__ sorted,
                                                float* __restrict__ aggx) {
    int bid = blockIdx.x;
    int g = bid & 7;
    int cc2 = bid >> 3;                   // 0..4999
    int pass = cc2 >= (NN / 4);
    int chunk = pass ? cc2 - NN / 4 : cc2;
    int wid = threadIdx.x >> 6, lane = threadIdx.x & 63;
    int r = chunk * 4 + wid;
    int bn = g * NN + r;
    int start = RFL(row_off[bn]);
    int cnt = RFL(row_cnt[bn]);
    const float* xb = x + (size_t)g * NN * CC + pass * 64 + lane;
    const long long* ep =
        (const long long*)(sorted + (size_t)g * NBKT * CAP + start);

    float acc = 0.f;
    int G = cnt >> 3;
    int e = 0;
    if (G >= 2) {
        long long rawE[8], rawO[8];
        float xvE[8], xvO[8];
        float vE[8], vO[8];
#pragma unroll
        for (int j = 0; j < 8; j++) rawE[j] = ep[j];
#pragma unroll
        for (int j = 0; j < 8; j++) rawO[j] = ep[8 + j];
        int cE[8], cO[8];
#pragma unroll
        for (int j = 0; j < 8; j++) {
            cE[j] = RFL((int)rawE[j]);
            vE[j] = __int_as_float(RFL((int)(rawE[j] >> 32)));
        }
#pragma unroll
        for (int j = 0; j < 8; j++) xvE[j] = xb[(size_t)cE[j] << 7];
#pragma unroll
        for (int j = 0; j < 8; j++) rawE[j] = ep[16 + j];

        int gi = 1;
        for (; gi + 1 < G; gi += 2) {
#pragma unroll
            for (int j = 0; j < 8; j++) {
                cO[j] = RFL((int)rawO[j]);
                vO[j] = __int_as_float(RFL((int)(rawO[j] >> 32)));
            }
#pragma unroll
            for (int j = 0; j < 8; j++) xvO[j] = xb[(size_t)cO[j] << 7];
#pragma unroll
            for (int j = 0; j < 8; j++) rawO[j] = ep[(gi + 2) * 8 + j];
#pragma unroll
            for (int j = 0; j < 8; j++) acc += vE[j] * xvE[j];
#pragma unroll
            for (int j = 0; j < 8; j++) {
                cE[j] = RFL((int)rawE[j]);
                vE[j] = __int_as_float(RFL((int)(rawE[j] >> 32)));
            }
#pragma unroll
            for (int j = 0; j < 8; j++) xvE[j] = xb[(size_t)cE[j] << 7];
#pragma unroll
            for (int j = 0; j < 8; j++) rawE[j] = ep[(gi + 3) * 8 + j];
#pragma unroll
            for (int j = 0; j < 8; j++) acc += vO[j] * xvO[j];
        }
        if (gi < G) {
#pragma unroll
            for (int j = 0; j < 8; j++) {
                cO[j] = RFL((int)rawO[j]);
                vO[j] = __int_as_float(RFL((int)(rawO[j] >> 32)));
            }
#pragma unroll
            for (int j = 0; j < 8; j++) xvO[j] = xb[(size_t)cO[j] << 7];
#pragma unroll
            for (int j = 0; j < 8; j++) acc += vE[j] * xvE[j];
#pragma unroll
            for (int j = 0; j < 8; j++) acc += vO[j] * xvO[j];
        } else {
#pragma unroll
            for (int j = 0; j < 8; j++) acc += vE[j] * xvE[j];
        }
        e = G * 8;
    }
    for (; e < cnt; e++) {
        long long m = ep[e];
        int c0 = RFL((int)m);
        float v0 = __int_as_float(RFL((int)(m >> 32)));
        acc += v0 * xb[(size_t)c0 << 7];
    }
    aggx[(size_t)bn * CC + pass * 64 + lane] = acc;
}

// out[row] = mask * (aggx[row] @ W + deg*bias) / max(deg,1)
// 64-row tile (grid 1250) + two 32 KB W k-halves (verified out of top-5).
__global__ __launch_bounds__(256) void k_gemm(float* __restrict__ io,
                                              const float* __restrict__ W,
                                              const float* __restrict__ bias,
                                              const float* __restrict__ deg,
                                              const int* __restrict__ num_nodes) {
    __shared__ float4 wl[64 * 32];            // 32 KB: wl[kl*32 + c4]
    int t = threadIdx.x;
    const float4* Wv = (const float4*)W;

    int row0 = blockIdx.x * 64;
    int cg = t & 15;                          // col groups: 4cg and 64+4cg
    int rg = t >> 4;                          // rows 4*rg .. 4*rg+3
    const float* ap = io + (size_t)(row0 + rg * 4) * CC;

    float acc[4][8] = {};
    for (int h = 0; h < 2; h++) {
        __syncthreads();                      // previous half fully consumed
#pragma unroll
        for (int i = 0; i < 8; i++)
            wl[t + i * 256] = Wv[h * 2048 + t + i * 256];
        __syncthreads();
        int kbase = h * 64;
        for (int kc = 0; kc < 64; kc += 4) {
            float4 a[4];
#pragma unroll
            for (int i = 0; i < 4; i++)
                a[i] = *(const float4*)(ap + (size_t)i * CC + kbase + kc);
#pragma unroll
            for (int kk = 0; kk < 4; kk++) {
                float4 w0 = wl[(kc + kk) * 32 + cg];
                float4 w1 = wl[(kc + kk) * 32 + 16 + cg];
#pragma unroll
                for (int i = 0; i < 4; i++) {
                    float av = (kk == 0) ? a[i].x : (kk == 1) ? a[i].y
                             : (kk == 2) ? a[i].z : a[i].w;
                    acc[i][0] += av * w0.x; acc[i][1] += av * w0.y;
                    acc[i][2] += av * w0.z; acc[i][3] += av * w0.w;
                    acc[i][4] += av * w1.x; acc[i][5] += av * w1.y;
                    acc[i][6] += av * w1.z; acc[i][7] += av * w1.w;
                }
            }
        }
    }

    float4 b0 = *(const float4*)(bias + cg * 4);
    float4 b1 = *(const float4*)(bias + 64 + cg * 4);
    float bb[8] = { b0.x, b0.y, b0.z, b0.w, b1.x, b1.y, b1.z, b1.w };

#pragma unroll
    for (int i = 0; i < 4; i++) {
        int grow = row0 + rg * 4 + i;
        int b = grow / NN;
        int r = grow - b * NN;
        float d = deg[grow];
        float sc = 1.0f / fmaxf(d, 1.0f);
        bool alive = r < num_nodes[b];
        float o[8];
#pragma unroll
        for (int j = 0; j < 8; j++)
            o[j] = alive ? (acc[i][j] + d * bb[j]) * sc : 0.0f;
        float* dst = io + (size_t)grow * CC;
        *(float4*)(dst + cg * 4)      = make_float4(o[0], o[1], o[2], o[3]);
        *(float4*)(dst + 64 + cg * 4) = make_float4(o[4], o[5], o[6], o[7]);
    }
}

extern "C" void kernel_launch(void* const* d_in, const int* in_sizes, int n_in,
                              void* d_out, int out_size, void* d_ws, size_t ws_size,
                              hipStream_t stream) {
    const float* x        = (const float*)d_in[0];
    const float* weight   = (const float*)d_in[1];
    const float* bias     = (const float*)d_in[2];
    const int*   edge_row = (const int*)d_in[3];
    const int*   edge_col = (const int*)d_in[4];
    const float* edge_val = (const float*)d_in[5];
    const int*   num_nodes= (const int*)d_in[6];
    float* out = (float*)d_out;

    int2*  binned  = (int2*)d_out;                      // phase-A scratch in d_out
    int2*  sorted  = (int2*)d_ws;                       // BG*NBKT*CAP int2
    float* deg     = (float*)(sorted + (size_t)BG * NBKT * CAP);
    int*   row_off = (int*)(deg + BN);
    int*   row_cnt = row_off + BN;
    int*   cursor  = row_cnt + BN;                      // BG*NBKT ints

    hipMemsetAsync(cursor, 0, BG * NBKT * sizeof(int), stream);
    k_bin<<<BG * BPG, 256, 0, stream>>>(edge_row, edge_col, edge_val, cursor, binned);
    k_sort<<<BG * NBKT, 256, 0, stream>>>(binned, cursor, sorted,
                                          row_off, row_cnt, deg);
    k_gather<<<16 * (NN / 4), 256, 0, stream>>>(x, row_off, row_cnt, sorted, out);
    k_gemm<<<BN / 64, 256, 0, stream>>>(out, weight, bias, deg, num_nodes);
}